// Round 17
// baseline (456.277 us; speedup 1.0000x reference)
//
#include <hip/hip_runtime.h>
#include <hip/hip_bf16.h>

namespace {

constexpr int D_      = 1024;
constexpr int THREE_D = 3072;
constexpr int B_      = 8;
constexpr int M_      = 16384;   // B*L tokens

typedef unsigned short u16;
typedef __attribute__((ext_vector_type(8))) short bf16x8;
typedef __attribute__((ext_vector_type(4))) float f32x4;

__device__ __forceinline__ u16 f2bf(float f) {
  unsigned u = __float_as_uint(f);
  u += 0x7fffu + ((u >> 16) & 1u);   // round-to-nearest-even
  return (u16)(u >> 16);
}

// tanh-form gelu via native v_exp_f32; |err| <= ~3e-3 vs erf-gelu.
__device__ __forceinline__ float gelu_fast(float x) {
  float u = 0.7978845608028654f * (x + 0.044715f * x * x * x);
  float e = __expf(2.0f * u);
  float th = 1.0f - 2.0f * __builtin_amdgcn_rcpf(e + 1.0f);
  return 0.5f * x * (1.0f + th);
}

// direct global->LDS 16B async copy. LDS dest is wave-uniform base + lane*16.
typedef __attribute__((address_space(3))) unsigned int   lds_uint;
typedef const __attribute__((address_space(1))) unsigned int gl_uint;
__device__ __forceinline__ void gload16(const void* g, void* l) {
  __builtin_amdgcn_global_load_lds((gl_uint*)g, (lds_uint*)l, 16, 0, 0);
}

// inline-asm ds_read_b128 (opaque to compiler waitcnt pass; avoids the
// implicit vmcnt(0) drain before plain-C++ LDS reads when global_load_lds
// is outstanding — mechanism confirmed r15/r16).
typedef __attribute__((address_space(3))) const u16 lds_cu16;
__device__ __forceinline__ bf16x8 ds_read128(const u16* p) {
  bf16x8 r;
  asm volatile("ds_read_b128 %0, %1" : "=v"(r) : "v"((lds_cu16*)p));
  return r;
}

#define BAR() asm volatile("s_barrier" ::: "memory")
#define LGKM0() do { asm volatile("s_waitcnt lgkmcnt(0)" ::: "memory"); \
                     __builtin_amdgcn_sched_barrier(0); } while (0)

// ---------- weight transpose + f32->bf16 pack ----------
__global__ void packT(const float* __restrict__ s0, const float* __restrict__ s1,
                      u16* __restrict__ dst, int K, int N, int mode) {
  __shared__ float tile[32][33];
  int n0 = blockIdx.x * 32, k0 = blockIdx.y * 32;
  int tx = threadIdx.x, ty = threadIdx.y;
  for (int i = ty; i < 32; i += 8) {
    int k = k0 + i, n = n0 + tx;
    float v;
    if (mode == 1)      { int h = N >> 1; v = (n < h) ? s0[(size_t)k * h + n] : s1[(size_t)k * h + (n - h)]; }
    else if (mode == 2) { int h = K >> 1; v = (k < h) ? s0[(size_t)k * N + n] : s1[(size_t)(k - h) * N + n]; }
    else                v = s0[(size_t)k * N + n];
    tile[i][tx] = v;
  }
  __syncthreads();
  for (int i = ty; i < 32; i += 8) {
    int n = n0 + i, k = k0 + tx;
    dst[(size_t)n * K + k] = f2bf(tile[tx][i]);
  }
}

// ---------- ada embedding, K-split ----------
__global__ __launch_bounds__(256) void ada_part(const float* __restrict__ t,
                                                const float* __restrict__ W,
                                                float* __restrict__ part) {
  __shared__ float s[B_ * 256];
  const int jb = blockIdx.x, kc = blockIdx.y;
  const int tid = threadIdx.x;
  const int k0 = kc * 256;
  for (int idx = tid; idx < B_ * 256; idx += 256) {
    float v = t[((idx >> 8) << 10) + k0 + (idx & 255)];
    s[idx] = v / (1.0f + expf(-v));
  }
  __syncthreads();
  const int j = jb * 256 + tid;
  float acc[B_];
#pragma unroll
  for (int b = 0; b < B_; ++b) acc[b] = 0.f;
  for (int k = 0; k < 256; ++k) {
    const float w = W[(size_t)(k0 + k) * THREE_D + j];
#pragma unroll
    for (int b = 0; b < B_; ++b) acc[b] = fmaf(s[(b << 8) + k], w, acc[b]);
  }
#pragma unroll
  for (int b = 0; b < B_; ++b)
    part[((size_t)kc * B_ + b) * THREE_D + j] = acc[b];
}

__global__ __launch_bounds__(256) void ada_reduce(const float* __restrict__ part,
                                                  const float* __restrict__ bias,
                                                  float* __restrict__ out) {
  const int j = blockIdx.x * 256 + threadIdx.x;
  const int b = blockIdx.y;
  float v = bias[j];
#pragma unroll
  for (int kc = 0; kc < 4; ++kc) v += part[((size_t)kc * B_ + b) * THREE_D + j];
  out[(size_t)b * THREE_D + j] = v;
}

// ---------- LayerNorm + adaLN modulate -> bf16 ----------
__global__ __launch_bounds__(256) void ln_mod(const float* __restrict__ in,
                                              const float* __restrict__ modv,
                                              u16* __restrict__ out) {
  const int row = blockIdx.x;
  const int b = row >> 11;  // L = 2048
  const int tid = threadIdx.x;
  const float4 v = *(const float4*)(in + (size_t)row * D_ + tid * 4);
  float s = v.x + v.y + v.z + v.w;
  float q = v.x * v.x + v.y * v.y + v.z * v.z + v.w * v.w;
#pragma unroll
  for (int off = 32; off > 0; off >>= 1) {
    s += __shfl_down(s, off);
    q += __shfl_down(q, off);
  }
  __shared__ float red[8];
  const int wave = tid >> 6, lane = tid & 63;
  if (lane == 0) { red[wave] = s; red[4 + wave] = q; }
  __syncthreads();
  float ts = red[0] + red[1] + red[2] + red[3];
  float tq = red[4] + red[5] + red[6] + red[7];
  const float mu = ts * (1.0f / D_);
  const float var = tq * (1.0f / D_) - mu * mu;
  const float rstd = rsqrtf(var + 1e-6f);
  const float4 sh = *(const float4*)(modv + (size_t)b * THREE_D + tid * 4);
  const float4 sc = *(const float4*)(modv + (size_t)b * THREE_D + D_ + tid * 4);
  float o0 = (v.x - mu) * rstd * (1.0f + sc.x) + sh.x;
  float o1 = (v.y - mu) * rstd * (1.0f + sc.y) + sh.y;
  float o2 = (v.z - mu) * rstd * (1.0f + sc.z) + sh.z;
  float o3 = (v.w - mu) * rstd * (1.0f + sc.w) + sh.w;
  uint2 pk;
  pk.x = (unsigned)f2bf(o0) | ((unsigned)f2bf(o1) << 16);
  pk.y = (unsigned)f2bf(o2) | ((unsigned)f2bf(o3) << 16);
  *(uint2*)(out + (size_t)row * D_ + tid * 4) = pk;
}

// ---------- bf16 MFMA GEMM, 256x256, 8 waves, read-pipelined 4 phases ------
// Round-17: reads issued ONE PHASE AHEAD (after prior MFMA cluster), so each
// phase's lgkmcnt(0) is covered by ~620 cyc of MFMA and read-address VALU
// falls in the MFMA shadow. Staging 2 gloads/phase.
//
// Read sets (per wave): R0={af0:Aq(2wr) ks0, bf0:Bq(wc) ks0}
//   R1={af1:Aq(2wr) ks1, bf1:Bq(wc) ks1}  R2={af0:Aq(2wr+1) ks0}
//   R3={af1:Aq(2wr+1) ks1}.   L={B0..B3,A0,A2}, M={A1,A3}.
// Per-wave FIFO ledger (invariant at tile start: outstanding = M_t = 2):
//  ph0: lgkm0(R0); MFMA(af0,bf0->acc[0:4]); stage B0'B1' (->4); issue R1
//  ph1: lgkm0(R1); MFMA(af1,bf1->acc[0:4]); stage B2'B3' (->6);
//       vmcnt(4) retires M_t (2-ph distance); BAR publishes M_t; issue R2
//  ph2: lgkm0(R2); MFMA(af0q1,bf0->acc[4:8]); stage A0'A2' (->6); issue R3
//  ph3: lgkm0(R3); MFMA(af1q1,bf1->acc[4:8]); stage A1'A3' (->8);
//       vmcnt(2) retires L'={B'x4,A0',A2'}; BAR publishes L'; issue R0'(buf^1)
// RAW: every read-issue point follows the barrier publishing its data
//  (R0'@ph3-post-BAR reads L'; R2@ph1-post-BAR reads M_t; R1 reads same
//  quarters as R0). WAR: quarter q of buf^1 staged only after the barrier
//  that follows ALL waves' last lgkm0-completed reads of q (B,A02 via ph1
//  BAR of prior tile; A13 via ph3 BAR) — audited per-quarter.
constexpr int BM = 256, BN = 256, BK = 64;

template <int EPI, int NN, int KK>
__global__ __launch_bounds__(512, 2)
void gemm_bt(const u16* __restrict__ A, const u16* __restrict__ Bt,
             const float* __restrict__ b0, const float* __restrict__ b1,
             const float* __restrict__ xres, const int* __restrict__ mask,
             const float* __restrict__ gate,
             float* __restrict__ outf, u16* __restrict__ outh) {
  __shared__ u16 As[2][BM * BK];
  __shared__ u16 Bs[2][BN * BK];
  const int tid = threadIdx.x;
  const int wave = tid >> 6, lane = tid & 63;
  const int wr = wave >> 2, wc = wave & 3;
  const int l15 = lane & 15, l4 = lane >> 4;

  constexpr int LGX = (NN == 2048) ? 3 : 2;
  const int nwg = gridDim.x;
  const int flat = blockIdx.x;
  const int swz = (flat & 7) * (nwg >> 3) + (flat >> 3);
  const int bx = swz & ((1 << LGX) - 1), by = swz >> LGX;
  const int m0 = by * BM, n0 = bx * BN;

  const int sg = (lane & 7) ^ (lane >> 3);       // inverse-XOR global slot
  const int srow = wave * 8 + (lane >> 3);
  const u16* ga = A  + (size_t)(m0 + srow) * KK + sg * 8;
  const u16* gb = Bt + (size_t)(n0 + srow) * KK + sg * 8;
  const int ldq = wave * 8 * BK;

  const int swz0 = ((l4 ^ (l15 & 7)) << 3);
  const int swz1 = (((4 + l4) ^ (l15 & 7)) << 3);
  const int arow = (wr * 128 + l15) * BK;
  const int brow = (wc * 64 + l15) * BK;

  f32x4 acc[8][4];
#pragma unroll
  for (int i = 0; i < 8; ++i)
#pragma unroll
    for (int j = 0; j < 4; ++j) acc[i][j] = (f32x4){0.f, 0.f, 0.f, 0.f};

  constexpr int NT = KK / BK;

#define STG_A(q, dst, gp) gload16((gp) + (size_t)((q) * 64) * KK, (dst) + ((q) * 64) * BK + ldq)
#define STG_B(q, dst, gp) gload16((gp) + (size_t)((q) * 64) * KK, (dst) + ((q) * 64) * BK + ldq)

  bf16x8 af0[4], af1[4], bf0[4], bf1[4];

#define READ0(as_, bs_) do { \
  _Pragma("unroll") for (int i = 0; i < 4; ++i) af0[i] = ds_read128((as_) + arow + i * 16 * BK + swz0); \
  _Pragma("unroll") for (int j = 0; j < 4; ++j) bf0[j] = ds_read128((bs_) + brow + j * 16 * BK + swz0); } while (0)
#define READ1(as_, bs_) do { \
  _Pragma("unroll") for (int i = 0; i < 4; ++i) af1[i] = ds_read128((as_) + arow + i * 16 * BK + swz1); \
  _Pragma("unroll") for (int j = 0; j < 4; ++j) bf1[j] = ds_read128((bs_) + brow + j * 16 * BK + swz1); } while (0)
#define READ2(as_) do { \
  _Pragma("unroll") for (int i = 0; i < 4; ++i) af0[i] = ds_read128((as_) + arow + (64 + i * 16) * BK + swz0); } while (0)
#define READ3(as_) do { \
  _Pragma("unroll") for (int i = 0; i < 4; ++i) af1[i] = ds_read128((as_) + arow + (64 + i * 16) * BK + swz1); } while (0)

  // prologue: stage tile 0 (L then M), confirm L, publish, issue R0
  STG_B(0, Bs[0], gb); STG_B(1, Bs[0], gb); STG_B(2, Bs[0], gb); STG_B(3, Bs[0], gb);
  STG_A(0, As[0], ga); STG_A(2, As[0], ga);
  STG_A(1, As[0], ga); STG_A(3, As[0], ga);
  asm volatile("s_waitcnt vmcnt(2)" ::: "memory");
  BAR();
  READ0(As[0], Bs[0]);

  const u16* gan = ga + BK;
  const u16* gbn = gb + BK;

  for (int t = 0; t < NT; ++t) {
    const u16* as = As[t & 1];
    const u16* bs = Bs[t & 1];
    u16* An = As[(t + 1) & 1];
    u16* Bn = Bs[(t + 1) & 1];
    const bool pre = (t + 1 < NT);

    // ---- ph0 ----
    LGKM0();
    __builtin_amdgcn_s_setprio(1);
#pragma unroll
    for (int i = 0; i < 4; ++i)
#pragma unroll
      for (int j = 0; j < 4; ++j)
        acc[i][j] = __builtin_amdgcn_mfma_f32_16x16x32_bf16(af0[i], bf0[j], acc[i][j], 0, 0, 0);
    __builtin_amdgcn_s_setprio(0);
    if (pre) { STG_B(0, Bn, gbn); STG_B(1, Bn, gbn); }
    READ1(as, bs);

    // ---- ph1 ----
    LGKM0();
    __builtin_amdgcn_s_setprio(1);
#pragma unroll
    for (int i = 0; i < 4; ++i)
#pragma unroll
      for (int j = 0; j < 4; ++j)
        acc[i][j] = __builtin_amdgcn_mfma_f32_16x16x32_bf16(af1[i], bf1[j], acc[i][j], 0, 0, 0);
    __builtin_amdgcn_s_setprio(0);
    if (pre) {
      STG_B(2, Bn, gbn); STG_B(3, Bn, gbn);
      asm volatile("s_waitcnt vmcnt(4)" ::: "memory");   // M_t lands
    } else {
      asm volatile("s_waitcnt vmcnt(0)" ::: "memory");
    }
    BAR();                                               // publish M_t
    READ2(as);

    // ---- ph2 ----
    LGKM0();
    __builtin_amdgcn_s_setprio(1);
#pragma unroll
    for (int i = 0; i < 4; ++i)
#pragma unroll
      for (int j = 0; j < 4; ++j)
        acc[4 + i][j] = __builtin_amdgcn_mfma_f32_16x16x32_bf16(af0[i], bf0[j], acc[4 + i][j], 0, 0, 0);
    __builtin_amdgcn_s_setprio(0);
    if (pre) { STG_A(0, An, gan); STG_A(2, An, gan); }
    READ3(as);

    // ---- ph3 ----
    LGKM0();
    __builtin_amdgcn_s_setprio(1);
#pragma unroll
    for (int i = 0; i < 4; ++i)
#pragma unroll
      for (int j = 0; j < 4; ++j)
        acc[4 + i][j] = __builtin_amdgcn_mfma_f32_16x16x32_bf16(af1[i], bf1[j], acc[4 + i][j], 0, 0, 0);
    __builtin_amdgcn_s_setprio(0);
    if (pre) {
      STG_A(1, An, gan); STG_A(3, An, gan);
      asm volatile("s_waitcnt vmcnt(2)" ::: "memory");   // L_{t+1} lands
      BAR();                                             // publish L_{t+1}
      READ0(An, Bn);
      gan += BK; gbn += BK;
    }
  }
#undef STG_A
#undef STG_B
#undef READ0
#undef READ1
#undef READ2
#undef READ3

#pragma unroll
  for (int i = 0; i < 8; ++i) {
#pragma unroll
    for (int r = 0; r < 4; ++r) {
      const int m = m0 + wr * 128 + i * 16 + l4 * 4 + r;
#pragma unroll
      for (int j = 0; j < 4; ++j) {
        const int n = n0 + wc * 64 + j * 16 + l15;
        float v = acc[i][j][r];
        if constexpr (EPI == 0 || EPI == 1) {
          v += (n < (NN >> 1)) ? b0[n] : b1[n - (NN >> 1)];
          outh[(size_t)m * NN + n] = f2bf(gelu_fast(v));
        } else if constexpr (EPI == 2) {
          v += b0[n] + b1[n];
          float res = xres[(size_t)m * NN + n];
          if (mask[m] != 0) res += gate[(size_t)(m >> 11) * THREE_D + n] * v;
          outf[(size_t)m * NN + n] = res;
        } else {
          v += b0[n];
          outf[(size_t)m * NN + n] = outf[(size_t)m * NN + n] +
                                     gate[(size_t)(m >> 11) * THREE_D + n] * v;
        }
      }
    }
  }
}

}  // namespace

extern "C" void kernel_launch(void* const* d_in, const int* in_sizes, int n_in,
                              void* d_out, int out_size, void* d_ws, size_t ws_size,
                              hipStream_t stream) {
  const float* x       = (const float*)d_in[0];
  const float* t       = (const float*)d_in[1];
  const int*   mask    = (const int*)d_in[2];
  const float* ada_w   = (const float*)d_in[3];
  const float* ada_b   = (const float*)d_in[4];
  const float* ssm_w1  = (const float*)d_in[5];
  const float* ssm_b1  = (const float*)d_in[6];
  const float* ssm_w2  = (const float*)d_in[7];
  const float* ssm_b2  = (const float*)d_in[8];
  const float* bwd_w1  = (const float*)d_in[9];
  const float* bwd_b1  = (const float*)d_in[10];
  const float* bwd_w2  = (const float*)d_in[11];
  const float* bwd_b2  = (const float*)d_in[12];
  const float* ffada_w = (const float*)d_in[13];
  const float* ffada_b = (const float*)d_in[14];
  const float* ff_w1   = (const float*)d_in[15];
  const float* ff_b1   = (const float*)d_in[16];
  const float* ff_w2   = (const float*)d_in[17];
  const float* ff_b2   = (const float*)d_in[18];
  float* out = (float*)d_out;

  char* ws = (char*)d_ws;
  u16* normb = (u16*)ws;                                        // 16384*1024 bf16 (32 MB)
  u16* Hb    = (u16*)(ws + (size_t)M_ * D_ * 2);                // 16384*2048 bf16 (64 MB)
  u16* w1t   = (u16*)(ws + (size_t)M_ * D_ * 2 + (size_t)M_ * 2 * D_ * 2);
  u16* w2t   = w1t + (size_t)2 * D_ * D_;
  u16* fw1t  = w2t + (size_t)2 * D_ * D_;
  u16* fw2t  = fw1t + (size_t)2 * D_ * D_;
  float* emb   = (float*)(fw2t + (size_t)2 * D_ * D_);          // [8][3072]
  float* ffada = emb + B_ * THREE_D;                            // [8][3072]
  float* part0 = (float*)Hb;                                    // [4][8][3072]
  float* part1 = part0 + 4 * B_ * THREE_D;

  dim3 tb(32, 8);
  packT<<<dim3(64, 32), tb, 0, stream>>>(ssm_w1, bwd_w1, w1t, D_, 2 * D_, 1);
  packT<<<dim3(32, 64), tb, 0, stream>>>(ssm_w2, bwd_w2, w2t, 2 * D_, D_, 2);
  packT<<<dim3(64, 32), tb, 0, stream>>>(ff_w1, nullptr, fw1t, D_, 2 * D_, 0);
  packT<<<dim3(32, 64), tb, 0, stream>>>(ff_w2, nullptr, fw2t, 2 * D_, D_, 0);

  ada_part<<<dim3(12, 4), 256, 0, stream>>>(t, ada_w, part0);
  ada_part<<<dim3(12, 4), 256, 0, stream>>>(t, ffada_w, part1);
  ada_reduce<<<dim3(12, 8), 256, 0, stream>>>(part0, ada_b, emb);
  ada_reduce<<<dim3(12, 8), 256, 0, stream>>>(part1, ffada_b, ffada);

  ln_mod<<<M_, 256, 0, stream>>>(x, emb, normb);

  // H = gelu(norm @ W1cat + b1cat)                [16384 x 2048]
  gemm_bt<0, 2048, 1024><<<512, 512, 0, stream>>>(normb, w1t,
                                                  ssm_b1, bwd_b1, nullptr, nullptr, nullptr,
                                                  nullptr, Hb);
  // x_mid = x + mask*gate_msa*(H @ W2cat + b2sum) -> d_out
  gemm_bt<2, 1024, 2048><<<256, 512, 0, stream>>>(Hb, w2t,
                                                  ssm_b2, bwd_b2, x, mask, emb + 2 * D_,
                                                  out, nullptr);
  ln_mod<<<M_, 256, 0, stream>>>(out, ffada, normb);

  // H = gelu(ff_norm @ ff_w1 + ff_b1)             [16384 x 2048]
  gemm_bt<1, 2048, 1024><<<512, 512, 0, stream>>>(normb, fw1t,
                                                  ff_b1, ff_b1 + D_, nullptr, nullptr, nullptr,
                                                  nullptr, Hb);
  // out = x_mid + gate_mlp*(H @ ff_w2 + ff_b2)    (in-place on d_out)
  gemm_bt<3, 1024, 2048><<<256, 512, 0, stream>>>(Hb, fw2t,
                                                  ff_b2, nullptr, nullptr, nullptr, ffada + 2 * D_,
                                                  out, nullptr);
}

// Round 18
// 436.970 us; speedup vs baseline: 1.0442x; 1.0442x over previous
//
#include <hip/hip_runtime.h>
#include <hip/hip_bf16.h>

namespace {

constexpr int D_      = 1024;
constexpr int THREE_D = 3072;
constexpr int B_      = 8;
constexpr int M_      = 16384;   // B*L tokens

typedef unsigned short u16;
typedef __attribute__((ext_vector_type(8))) short bf16x8;
typedef __attribute__((ext_vector_type(4))) float f32x4;

__device__ __forceinline__ u16 f2bf(float f) {
  unsigned u = __float_as_uint(f);
  u += 0x7fffu + ((u >> 16) & 1u);   // round-to-nearest-even
  return (u16)(u >> 16);
}

__device__ __forceinline__ float gelu_fast(float x) {
  float u = 0.7978845608028654f * (x + 0.044715f * x * x * x);
  float e = __expf(2.0f * u);
  float th = 1.0f - 2.0f * __builtin_amdgcn_rcpf(e + 1.0f);
  return 0.5f * x * (1.0f + th);
}

typedef __attribute__((address_space(3))) unsigned int   lds_uint;
typedef const __attribute__((address_space(1))) unsigned int gl_uint;
__device__ __forceinline__ void gload16(const void* g, void* l) {
  __builtin_amdgcn_global_load_lds((gl_uint*)g, (lds_uint*)l, 16, 0, 0);
}

// inline-asm ds_read_b128 (avoids compiler's implicit vmcnt(0) drain before
// plain LDS reads while global_load_lds is outstanding — r15/r16 confirmed).
typedef __attribute__((address_space(3))) const u16 lds_cu16;
__device__ __forceinline__ bf16x8 ds_read128(const u16* p) {
  bf16x8 r;
  asm volatile("ds_read_b128 %0, %1" : "=v"(r) : "v"((lds_cu16*)p));
  return r;
}

#define BAR() asm volatile("s_barrier" ::: "memory")
#define LGKM0() do { asm volatile("s_waitcnt lgkmcnt(0)" ::: "memory"); \
                     __builtin_amdgcn_sched_barrier(0); } while (0)

// ---------- weight transpose + f32->bf16 pack ----------
__global__ void packT(const float* __restrict__ s0, const float* __restrict__ s1,
                      u16* __restrict__ dst, int K, int N, int mode) {
  __shared__ float tile[32][33];
  int n0 = blockIdx.x * 32, k0 = blockIdx.y * 32;
  int tx = threadIdx.x, ty = threadIdx.y;
  for (int i = ty; i < 32; i += 8) {
    int k = k0 + i, n = n0 + tx;
    float v;
    if (mode == 1)      { int h = N >> 1; v = (n < h) ? s0[(size_t)k * h + n] : s1[(size_t)k * h + (n - h)]; }
    else if (mode == 2) { int h = K >> 1; v = (k < h) ? s0[(size_t)k * N + n] : s1[(size_t)(k - h) * N + n]; }
    else                v = s0[(size_t)k * N + n];
    tile[i][tx] = v;
  }
  __syncthreads();
  for (int i = ty; i < 32; i += 8) {
    int n = n0 + i, k = k0 + tx;
    dst[(size_t)n * K + k] = f2bf(tile[tx][i]);
  }
}

// ---------- ada embedding, K-split ----------
__global__ __launch_bounds__(256) void ada_part(const float* __restrict__ t,
                                                const float* __restrict__ W,
                                                float* __restrict__ part) {
  __shared__ float s[B_ * 256];
  const int jb = blockIdx.x, kc = blockIdx.y;
  const int tid = threadIdx.x;
  const int k0 = kc * 256;
  for (int idx = tid; idx < B_ * 256; idx += 256) {
    float v = t[((idx >> 8) << 10) + k0 + (idx & 255)];
    s[idx] = v / (1.0f + expf(-v));
  }
  __syncthreads();
  const int j = jb * 256 + tid;
  float acc[B_];
#pragma unroll
  for (int b = 0; b < B_; ++b) acc[b] = 0.f;
  for (int k = 0; k < 256; ++k) {
    const float w = W[(size_t)(k0 + k) * THREE_D + j];
#pragma unroll
    for (int b = 0; b < B_; ++b) acc[b] = fmaf(s[(b << 8) + k], w, acc[b]);
  }
#pragma unroll
  for (int b = 0; b < B_; ++b)
    part[((size_t)kc * B_ + b) * THREE_D + j] = acc[b];
}

__global__ __launch_bounds__(256) void ada_reduce(const float* __restrict__ part,
                                                  const float* __restrict__ bias,
                                                  float* __restrict__ out) {
  const int j = blockIdx.x * 256 + threadIdx.x;
  const int b = blockIdx.y;
  float v = bias[j];
#pragma unroll
  for (int kc = 0; kc < 4; ++kc) v += part[((size_t)kc * B_ + b) * THREE_D + j];
  out[(size_t)b * THREE_D + j] = v;
}

// ---------- mask compaction ----------
// SSM stage output is discarded for mask==0 tokens (x_mid = x exactly), so
// gemm0/gemm2 only need the ~50% mask==1 rows. Compaction order is
// nondeterministic (atomicAdd) but per-row arithmetic is position-independent
// -> output is bitwise deterministic.
__global__ __launch_bounds__(256) void compact_mask(const int* __restrict__ mask,
                                                    int* __restrict__ cnt,
                                                    int* __restrict__ cidx) {
  const int m = blockIdx.x * 256 + threadIdx.x;
  if (mask[m] != 0) {
    int p = atomicAdd(cnt, 1);
    cidx[p] = m;
  }
}

// pad to a 256-multiple: tail cidx=-1, tail normc rows zeroed, store M_pad.
__global__ __launch_bounds__(256) void pad_tail(const int* __restrict__ cnt,
                                                int* __restrict__ cidx,
                                                u16* __restrict__ normc,
                                                int* __restrict__ mpad) {
  const int c = *cnt;
  const int pad = (c + 255) & ~255;
  if (blockIdx.x == 0 && threadIdx.x == 0) *mpad = pad;
  const int p = c + blockIdx.x;
  if (p < pad) {
    if (threadIdx.x == 0) cidx[p] = -1;
    ((uint2*)(normc + (size_t)p * D_))[threadIdx.x] = (uint2){0u, 0u};
  }
}

// out[row] = x[row] for mask==0 rows
__global__ __launch_bounds__(256) void copy_unmasked(const float* __restrict__ x,
                                                     const int* __restrict__ mask,
                                                     float* __restrict__ out) {
  const int row = blockIdx.x;
  if (mask[row] != 0) return;
  const int tid = threadIdx.x;
  *(float4*)(out + (size_t)row * D_ + tid * 4) =
      *(const float4*)(x + (size_t)row * D_ + tid * 4);
}

// ---------- LayerNorm + adaLN modulate -> bf16 (full M) ----------
__global__ __launch_bounds__(256) void ln_mod(const float* __restrict__ in,
                                              const float* __restrict__ modv,
                                              u16* __restrict__ out) {
  const int row = blockIdx.x;
  const int b = row >> 11;  // L = 2048
  const int tid = threadIdx.x;
  const float4 v = *(const float4*)(in + (size_t)row * D_ + tid * 4);
  float s = v.x + v.y + v.z + v.w;
  float q = v.x * v.x + v.y * v.y + v.z * v.z + v.w * v.w;
#pragma unroll
  for (int off = 32; off > 0; off >>= 1) {
    s += __shfl_down(s, off);
    q += __shfl_down(q, off);
  }
  __shared__ float red[8];
  const int wave = tid >> 6, lane = tid & 63;
  if (lane == 0) { red[wave] = s; red[4 + wave] = q; }
  __syncthreads();
  float ts = red[0] + red[1] + red[2] + red[3];
  float tq = red[4] + red[5] + red[6] + red[7];
  const float mu = ts * (1.0f / D_);
  const float var = tq * (1.0f / D_) - mu * mu;
  const float rstd = rsqrtf(var + 1e-6f);
  const float4 sh = *(const float4*)(modv + (size_t)b * THREE_D + tid * 4);
  const float4 sc = *(const float4*)(modv + (size_t)b * THREE_D + D_ + tid * 4);
  float o0 = (v.x - mu) * rstd * (1.0f + sc.x) + sh.x;
  float o1 = (v.y - mu) * rstd * (1.0f + sc.y) + sh.y;
  float o2 = (v.z - mu) * rstd * (1.0f + sc.z) + sh.z;
  float o3 = (v.w - mu) * rstd * (1.0f + sc.w) + sh.w;
  uint2 pk;
  pk.x = (unsigned)f2bf(o0) | ((unsigned)f2bf(o1) << 16);
  pk.y = (unsigned)f2bf(o2) | ((unsigned)f2bf(o3) << 16);
  *(uint2*)(out + (size_t)row * D_ + tid * 4) = pk;
}

// compacted variant: p -> row = cidx[p]; writes normc[p]
__global__ __launch_bounds__(256) void ln_mod_idx(const float* __restrict__ in,
                                                  const float* __restrict__ modv,
                                                  const int* __restrict__ cnt,
                                                  const int* __restrict__ cidx,
                                                  u16* __restrict__ out) {
  const int p = blockIdx.x;
  if (p >= *cnt) return;
  const int row = cidx[p];
  const int b = row >> 11;
  const int tid = threadIdx.x;
  const float4 v = *(const float4*)(in + (size_t)row * D_ + tid * 4);
  float s = v.x + v.y + v.z + v.w;
  float q = v.x * v.x + v.y * v.y + v.z * v.z + v.w * v.w;
#pragma unroll
  for (int off = 32; off > 0; off >>= 1) {
    s += __shfl_down(s, off);
    q += __shfl_down(q, off);
  }
  __shared__ float red[8];
  const int wave = tid >> 6, lane = tid & 63;
  if (lane == 0) { red[wave] = s; red[4 + wave] = q; }
  __syncthreads();
  float ts = red[0] + red[1] + red[2] + red[3];
  float tq = red[4] + red[5] + red[6] + red[7];
  const float mu = ts * (1.0f / D_);
  const float var = tq * (1.0f / D_) - mu * mu;
  const float rstd = rsqrtf(var + 1e-6f);
  const float4 sh = *(const float4*)(modv + (size_t)b * THREE_D + tid * 4);
  const float4 sc = *(const float4*)(modv + (size_t)b * THREE_D + D_ + tid * 4);
  float o0 = (v.x - mu) * rstd * (1.0f + sc.x) + sh.x;
  float o1 = (v.y - mu) * rstd * (1.0f + sc.y) + sh.y;
  float o2 = (v.z - mu) * rstd * (1.0f + sc.z) + sh.z;
  float o3 = (v.w - mu) * rstd * (1.0f + sc.w) + sh.w;
  uint2 pk;
  pk.x = (unsigned)f2bf(o0) | ((unsigned)f2bf(o1) << 16);
  pk.y = (unsigned)f2bf(o2) | ((unsigned)f2bf(o3) << 16);
  *(uint2*)(out + (size_t)p * D_ + tid * 4) = pk;
}

// ---------- bf16 MFMA GEMM, 256x256, 8 waves (r16 schedule, best measured) -
// EPI 0: compacted A (early-exit on *mpad); outh = bf16(gelu(v + bias_split))
// EPI 1: full A; same epilogue
// EPI 2: compacted; row = cidx[p] (skip row<0); outf[row] = xres[row] + gate*v
// EPI 3: full; outf += gate*(v + b0)
constexpr int BM = 256, BN = 256, BK = 64;

template <int EPI, int NN, int KK>
__global__ __launch_bounds__(512, 2)
void gemm_bt(const u16* __restrict__ A, const u16* __restrict__ Bt,
             const float* __restrict__ b0, const float* __restrict__ b1,
             const float* __restrict__ xres, const int* __restrict__ cidx,
             const int* __restrict__ mpad,
             const float* __restrict__ gate,
             float* __restrict__ outf, u16* __restrict__ outh) {
  __shared__ u16 As[2][BM * BK];
  __shared__ u16 Bs[2][BN * BK];
  const int tid = threadIdx.x;
  const int wave = tid >> 6, lane = tid & 63;
  const int wr = wave >> 2, wc = wave & 3;
  const int l15 = lane & 15, l4 = lane >> 4;

  constexpr int LGX = (NN == 2048) ? 3 : 2;
  const int nwg = gridDim.x;
  const int flat = blockIdx.x;
  const int swz = (flat & 7) * (nwg >> 3) + (flat >> 3);
  const int bx = swz & ((1 << LGX) - 1), by = swz >> LGX;
  const int m0 = by * BM, n0 = bx * BN;

  if constexpr (EPI == 0 || EPI == 2) {
    if (m0 >= *mpad) return;     // compacted stage: data-dependent M
  }

  const int sg = (lane & 7) ^ (lane >> 3);
  const int srow = wave * 8 + (lane >> 3);
  const u16* ga = A  + (size_t)(m0 + srow) * KK + sg * 8;
  const u16* gb = Bt + (size_t)(n0 + srow) * KK + sg * 8;
  const int ldq = wave * 8 * BK;

  const int swz0 = ((l4 ^ (l15 & 7)) << 3);
  const int swz1 = (((4 + l4) ^ (l15 & 7)) << 3);
  const int arow = (wr * 128 + l15) * BK;
  const int brow = (wc * 64 + l15) * BK;

  f32x4 acc[8][4];
#pragma unroll
  for (int i = 0; i < 8; ++i)
#pragma unroll
    for (int j = 0; j < 4; ++j) acc[i][j] = (f32x4){0.f, 0.f, 0.f, 0.f};

  constexpr int NT = KK / BK;

#define STG_A(q, dst, gp) gload16((gp) + (size_t)((q) * 64) * KK, (dst) + ((q) * 64) * BK + ldq)
#define STG_B(q, dst, gp) gload16((gp) + (size_t)((q) * 64) * KK, (dst) + ((q) * 64) * BK + ldq)

  // prologue: stage tile 0 (L0 then M0), confirm L0, leave M0 flying
  STG_B(0, Bs[0], gb); STG_B(1, Bs[0], gb); STG_B(2, Bs[0], gb); STG_B(3, Bs[0], gb);
  STG_A(0, As[0], ga); STG_A(2, As[0], ga);
  STG_A(1, As[0], ga); STG_A(3, As[0], ga);
  asm volatile("s_waitcnt vmcnt(2)" ::: "memory");
  BAR();

  const u16* gan = ga + BK;
  const u16* gbn = gb + BK;

  bf16x8 af0[4], af1[4], bf0[4], bf1[4];
  for (int t = 0; t < NT; ++t) {
    const u16* as = As[t & 1];
    const u16* bs = Bs[t & 1];
    u16* An = As[(t + 1) & 1];
    u16* Bn = Bs[(t + 1) & 1];
    const bool pre = (t + 1 < NT);

    // ---- ph0 ----
#pragma unroll
    for (int i = 0; i < 4; ++i) af0[i] = ds_read128(as + arow + i * 16 * BK + swz0);
#pragma unroll
    for (int j = 0; j < 4; ++j) bf0[j] = ds_read128(bs + brow + j * 16 * BK + swz0);
    if (pre) { STG_B(0, Bn, gbn); STG_B(1, Bn, gbn); STG_B(2, Bn, gbn); STG_B(3, Bn, gbn); }
    LGKM0();
    __builtin_amdgcn_s_setprio(1);
#pragma unroll
    for (int i = 0; i < 4; ++i)
#pragma unroll
      for (int j = 0; j < 4; ++j)
        acc[i][j] = __builtin_amdgcn_mfma_f32_16x16x32_bf16(af0[i], bf0[j], acc[i][j], 0, 0, 0);
    __builtin_amdgcn_s_setprio(0);

    // ---- ph1 ----
#pragma unroll
    for (int i = 0; i < 4; ++i) af1[i] = ds_read128(as + arow + i * 16 * BK + swz1);
#pragma unroll
    for (int j = 0; j < 4; ++j) bf1[j] = ds_read128(bs + brow + j * 16 * BK + swz1);
    if (pre) {
      STG_A(0, An, gan); STG_A(2, An, gan);
      asm volatile("s_waitcnt vmcnt(6)" ::: "memory");   // M_t lands
    } else {
      asm volatile("s_waitcnt vmcnt(0)" ::: "memory");
    }
    BAR();
    LGKM0();
    __builtin_amdgcn_s_setprio(1);
#pragma unroll
    for (int i = 0; i < 4; ++i)
#pragma unroll
      for (int j = 0; j < 4; ++j)
        acc[i][j] = __builtin_amdgcn_mfma_f32_16x16x32_bf16(af1[i], bf1[j], acc[i][j], 0, 0, 0);
    __builtin_amdgcn_s_setprio(0);

    // ---- ph2 ----
#pragma unroll
    for (int i = 0; i < 4; ++i) af0[i] = ds_read128(as + arow + (64 + i * 16) * BK + swz0);
    if (pre) { STG_A(1, An, gan); STG_A(3, An, gan); }
    LGKM0();
    __builtin_amdgcn_s_setprio(1);
#pragma unroll
    for (int i = 0; i < 4; ++i)
#pragma unroll
      for (int j = 0; j < 4; ++j)
        acc[4 + i][j] = __builtin_amdgcn_mfma_f32_16x16x32_bf16(af0[i], bf0[j], acc[4 + i][j], 0, 0, 0);
    __builtin_amdgcn_s_setprio(0);

    // ---- ph3 ----
#pragma unroll
    for (int i = 0; i < 4; ++i) af1[i] = ds_read128(as + arow + (64 + i * 16) * BK + swz1);
    if (pre) asm volatile("s_waitcnt vmcnt(2)" ::: "memory");  // L_{t+1} lands
    BAR();
    LGKM0();
    __builtin_amdgcn_s_setprio(1);
#pragma unroll
    for (int i = 0; i < 4; ++i)
#pragma unroll
      for (int j = 0; j < 4; ++j)
        acc[4 + i][j] = __builtin_amdgcn_mfma_f32_16x16x32_bf16(af1[i], bf1[j], acc[4 + i][j], 0, 0, 0);
    __builtin_amdgcn_s_setprio(0);

    gan += BK; gbn += BK;
  }
#undef STG_A
#undef STG_B

#pragma unroll
  for (int i = 0; i < 8; ++i) {
#pragma unroll
    for (int r = 0; r < 4; ++r) {
      const int m = m0 + wr * 128 + i * 16 + l4 * 4 + r;   // compacted p for EPI 0/2
      int row = m;
      if constexpr (EPI == 2) {
        row = cidx[m];
        if (row < 0) continue;
      }
#pragma unroll
      for (int j = 0; j < 4; ++j) {
        const int n = n0 + wc * 64 + j * 16 + l15;
        float v = acc[i][j][r];
        if constexpr (EPI == 0 || EPI == 1) {
          v += (n < (NN >> 1)) ? b0[n] : b1[n - (NN >> 1)];
          outh[(size_t)m * NN + n] = f2bf(gelu_fast(v));
        } else if constexpr (EPI == 2) {
          v += b0[n] + b1[n];
          outf[(size_t)row * NN + n] = xres[(size_t)row * NN + n] +
                                       gate[(size_t)(row >> 11) * THREE_D + n] * v;
        } else {
          v += b0[n];
          outf[(size_t)m * NN + n] = outf[(size_t)m * NN + n] +
                                     gate[(size_t)(m >> 11) * THREE_D + n] * v;
        }
      }
    }
  }
}

}  // namespace

extern "C" void kernel_launch(void* const* d_in, const int* in_sizes, int n_in,
                              void* d_out, int out_size, void* d_ws, size_t ws_size,
                              hipStream_t stream) {
  const float* x       = (const float*)d_in[0];
  const float* t       = (const float*)d_in[1];
  const int*   mask    = (const int*)d_in[2];
  const float* ada_w   = (const float*)d_in[3];
  const float* ada_b   = (const float*)d_in[4];
  const float* ssm_w1  = (const float*)d_in[5];
  const float* ssm_b1  = (const float*)d_in[6];
  const float* ssm_w2  = (const float*)d_in[7];
  const float* ssm_b2  = (const float*)d_in[8];
  const float* bwd_w1  = (const float*)d_in[9];
  const float* bwd_b1  = (const float*)d_in[10];
  const float* bwd_w2  = (const float*)d_in[11];
  const float* bwd_b2  = (const float*)d_in[12];
  const float* ffada_w = (const float*)d_in[13];
  const float* ffada_b = (const float*)d_in[14];
  const float* ff_w1   = (const float*)d_in[15];
  const float* ff_b1   = (const float*)d_in[16];
  const float* ff_w2   = (const float*)d_in[17];
  const float* ff_b2   = (const float*)d_in[18];
  float* out = (float*)d_out;

  char* ws = (char*)d_ws;
  u16* normb = (u16*)ws;                                        // 16384*1024 bf16 (32 MB)
  u16* Hb    = (u16*)(ws + (size_t)M_ * D_ * 2);                // 16384*2048 bf16 (64 MB)
  u16* w1t   = (u16*)(ws + (size_t)M_ * D_ * 2 + (size_t)M_ * 2 * D_ * 2);
  u16* w2t   = w1t + (size_t)2 * D_ * D_;
  u16* fw1t  = w2t + (size_t)2 * D_ * D_;
  u16* fw2t  = fw1t + (size_t)2 * D_ * D_;
  float* emb   = (float*)(fw2t + (size_t)2 * D_ * D_);          // [8][3072]
  float* ffada = emb + B_ * THREE_D;                            // [8][3072]
  int* cnt   = (int*)(ffada + B_ * THREE_D);
  int* mpad  = cnt + 1;
  int* cidx  = mpad + 7;                                        // 16384 ints
  float* part0 = (float*)Hb;                                    // [4][8][3072]
  float* part1 = part0 + 4 * B_ * THREE_D;

  dim3 tb(32, 8);
  packT<<<dim3(64, 32), tb, 0, stream>>>(ssm_w1, bwd_w1, w1t, D_, 2 * D_, 1);
  packT<<<dim3(32, 64), tb, 0, stream>>>(ssm_w2, bwd_w2, w2t, 2 * D_, D_, 2);
  packT<<<dim3(64, 32), tb, 0, stream>>>(ff_w1, nullptr, fw1t, D_, 2 * D_, 0);
  packT<<<dim3(32, 64), tb, 0, stream>>>(ff_w2, nullptr, fw2t, 2 * D_, D_, 0);

  ada_part<<<dim3(12, 4), 256, 0, stream>>>(t, ada_w, part0);
  ada_part<<<dim3(12, 4), 256, 0, stream>>>(t, ffada_w, part1);
  ada_reduce<<<dim3(12, 8), 256, 0, stream>>>(part0, ada_b, emb);
  ada_reduce<<<dim3(12, 8), 256, 0, stream>>>(part1, ffada_b, ffada);

  // mask compaction for the SSM stage
  hipMemsetAsync(cnt, 0, sizeof(int), stream);
  compact_mask<<<64, 256, 0, stream>>>(mask, cnt, cidx);
  pad_tail<<<256, 256, 0, stream>>>(cnt, cidx, normb, mpad);
  copy_unmasked<<<M_, 256, 0, stream>>>(x, mask, out);          // x_mid = x for mask==0
  ln_mod_idx<<<M_, 256, 0, stream>>>(x, emb, cnt, cidx, normb); // compacted LN

  // H = gelu(norm @ W1cat + b1cat)   [M_pad x 2048], compacted rows
  gemm_bt<0, 2048, 1024><<<512, 512, 0, stream>>>(normb, w1t,
                                                  ssm_b1, bwd_b1, nullptr, nullptr, mpad, nullptr,
                                                  nullptr, Hb);
  // x_mid[row] = x[row] + gate_msa*(H @ W2cat + b2sum), scattered via cidx
  gemm_bt<2, 1024, 2048><<<256, 512, 0, stream>>>(Hb, w2t,
                                                  ssm_b2, bwd_b2, x, cidx, mpad, emb + 2 * D_,
                                                  out, nullptr);
  // ff stage: full M
  ln_mod<<<M_, 256, 0, stream>>>(out, ffada, normb);
  gemm_bt<1, 2048, 1024><<<512, 512, 0, stream>>>(normb, fw1t,
                                                  ff_b1, ff_b1 + D_, nullptr, nullptr, nullptr, nullptr,
                                                  nullptr, Hb);
  gemm_bt<3, 1024, 2048><<<256, 512, 0, stream>>>(Hb, fw2t,
                                                  ff_b2, nullptr, nullptr, nullptr, nullptr, ffada + 2 * D_,
                                                  out, nullptr);
}

// Round 19
// 394.860 us; speedup vs baseline: 1.1555x; 1.1066x over previous
//
#include <hip/hip_runtime.h>
#include <hip/hip_bf16.h>

namespace {

constexpr int D_      = 1024;
constexpr int THREE_D = 3072;
constexpr int B_      = 8;
constexpr int M_      = 16384;   // B*L tokens

typedef unsigned short u16;
typedef __attribute__((ext_vector_type(8))) short bf16x8;
typedef __attribute__((ext_vector_type(4))) float f32x4;

__device__ __forceinline__ u16 f2bf(float f) {
  unsigned u = __float_as_uint(f);
  u += 0x7fffu + ((u >> 16) & 1u);   // round-to-nearest-even
  return (u16)(u >> 16);
}

__device__ __forceinline__ float gelu_fast(float x) {
  float u = 0.7978845608028654f * (x + 0.044715f * x * x * x);
  float e = __expf(2.0f * u);
  float th = 1.0f - 2.0f * __builtin_amdgcn_rcpf(e + 1.0f);
  return 0.5f * x * (1.0f + th);
}

typedef __attribute__((address_space(3))) unsigned int   lds_uint;
typedef const __attribute__((address_space(1))) unsigned int gl_uint;
__device__ __forceinline__ void gload16(const void* g, void* l) {
  __builtin_amdgcn_global_load_lds((gl_uint*)g, (lds_uint*)l, 16, 0, 0);
}

// inline-asm ds_read_b128 (avoids compiler's implicit vmcnt(0) drain before
// plain LDS reads while global_load_lds is outstanding — r15/r16 confirmed).
typedef __attribute__((address_space(3))) const u16 lds_cu16;
__device__ __forceinline__ bf16x8 ds_read128(const u16* p) {
  bf16x8 r;
  asm volatile("ds_read_b128 %0, %1" : "=v"(r) : "v"((lds_cu16*)p));
  return r;
}

#define BAR() asm volatile("s_barrier" ::: "memory")
#define LGKM0() do { asm volatile("s_waitcnt lgkmcnt(0)" ::: "memory"); \
                     __builtin_amdgcn_sched_barrier(0); } while (0)

// ---------- weight transpose + f32->bf16 pack ----------
__global__ void packT(const float* __restrict__ s0, const float* __restrict__ s1,
                      u16* __restrict__ dst, int K, int N, int mode) {
  __shared__ float tile[32][33];
  int n0 = blockIdx.x * 32, k0 = blockIdx.y * 32;
  int tx = threadIdx.x, ty = threadIdx.y;
  for (int i = ty; i < 32; i += 8) {
    int k = k0 + i, n = n0 + tx;
    float v;
    if (mode == 1)      { int h = N >> 1; v = (n < h) ? s0[(size_t)k * h + n] : s1[(size_t)k * h + (n - h)]; }
    else if (mode == 2) { int h = K >> 1; v = (k < h) ? s0[(size_t)k * N + n] : s1[(size_t)(k - h) * N + n]; }
    else                v = s0[(size_t)k * N + n];
    tile[i][tx] = v;
  }
  __syncthreads();
  for (int i = ty; i < 32; i += 8) {
    int n = n0 + i, k = k0 + tx;
    dst[(size_t)n * K + k] = f2bf(tile[tx][i]);
  }
}

// ---------- ada embedding, K-split ----------
__global__ __launch_bounds__(256) void ada_part(const float* __restrict__ t,
                                                const float* __restrict__ W,
                                                float* __restrict__ part) {
  __shared__ float s[B_ * 256];
  const int jb = blockIdx.x, kc = blockIdx.y;
  const int tid = threadIdx.x;
  const int k0 = kc * 256;
  for (int idx = tid; idx < B_ * 256; idx += 256) {
    float v = t[((idx >> 8) << 10) + k0 + (idx & 255)];
    s[idx] = v / (1.0f + expf(-v));
  }
  __syncthreads();
  const int j = jb * 256 + tid;
  float acc[B_];
#pragma unroll
  for (int b = 0; b < B_; ++b) acc[b] = 0.f;
  for (int k = 0; k < 256; ++k) {
    const float w = W[(size_t)(k0 + k) * THREE_D + j];
#pragma unroll
    for (int b = 0; b < B_; ++b) acc[b] = fmaf(s[(b << 8) + k], w, acc[b]);
  }
#pragma unroll
  for (int b = 0; b < B_; ++b)
    part[((size_t)kc * B_ + b) * THREE_D + j] = acc[b];
}

__global__ __launch_bounds__(256) void ada_reduce(const float* __restrict__ part,
                                                  const float* __restrict__ bias,
                                                  float* __restrict__ out) {
  const int j = blockIdx.x * 256 + threadIdx.x;
  const int b = blockIdx.y;
  float v = bias[j];
#pragma unroll
  for (int kc = 0; kc < 4; ++kc) v += part[((size_t)kc * B_ + b) * THREE_D + j];
  out[(size_t)b * THREE_D + j] = v;
}

// ---------- mask compaction ----------
__global__ __launch_bounds__(256) void compact_mask(const int* __restrict__ mask,
                                                    int* __restrict__ cnt,
                                                    int* __restrict__ cidx) {
  const int m = blockIdx.x * 256 + threadIdx.x;
  if (mask[m] != 0) {
    int p = atomicAdd(cnt, 1);
    cidx[p] = m;
  }
}

__global__ __launch_bounds__(256) void pad_tail(const int* __restrict__ cnt,
                                                int* __restrict__ cidx,
                                                u16* __restrict__ normc,
                                                int* __restrict__ mpad) {
  const int c = *cnt;
  const int pad = (c + 255) & ~255;
  if (blockIdx.x == 0 && threadIdx.x == 0) *mpad = pad;
  const int p = c + blockIdx.x;
  if (p < pad) {
    if (threadIdx.x == 0) cidx[p] = -1;
    ((uint2*)(normc + (size_t)p * D_))[threadIdx.x] = (uint2){0u, 0u};
  }
}

__global__ __launch_bounds__(256) void copy_unmasked(const float* __restrict__ x,
                                                     const int* __restrict__ mask,
                                                     float* __restrict__ out) {
  const int row = blockIdx.x;
  if (mask[row] != 0) return;
  const int tid = threadIdx.x;
  *(float4*)(out + (size_t)row * D_ + tid * 4) =
      *(const float4*)(x + (size_t)row * D_ + tid * 4);
}

// ---------- LayerNorm + adaLN modulate -> bf16 (full M) ----------
__global__ __launch_bounds__(256) void ln_mod(const float* __restrict__ in,
                                              const float* __restrict__ modv,
                                              u16* __restrict__ out) {
  const int row = blockIdx.x;
  const int b = row >> 11;  // L = 2048
  const int tid = threadIdx.x;
  const float4 v = *(const float4*)(in + (size_t)row * D_ + tid * 4);
  float s = v.x + v.y + v.z + v.w;
  float q = v.x * v.x + v.y * v.y + v.z * v.z + v.w * v.w;
#pragma unroll
  for (int off = 32; off > 0; off >>= 1) {
    s += __shfl_down(s, off);
    q += __shfl_down(q, off);
  }
  __shared__ float red[8];
  const int wave = tid >> 6, lane = tid & 63;
  if (lane == 0) { red[wave] = s; red[4 + wave] = q; }
  __syncthreads();
  float ts = red[0] + red[1] + red[2] + red[3];
  float tq = red[4] + red[5] + red[6] + red[7];
  const float mu = ts * (1.0f / D_);
  const float var = tq * (1.0f / D_) - mu * mu;
  const float rstd = rsqrtf(var + 1e-6f);
  const float4 sh = *(const float4*)(modv + (size_t)b * THREE_D + tid * 4);
  const float4 sc = *(const float4*)(modv + (size_t)b * THREE_D + D_ + tid * 4);
  float o0 = (v.x - mu) * rstd * (1.0f + sc.x) + sh.x;
  float o1 = (v.y - mu) * rstd * (1.0f + sc.y) + sh.y;
  float o2 = (v.z - mu) * rstd * (1.0f + sc.z) + sh.z;
  float o3 = (v.w - mu) * rstd * (1.0f + sc.w) + sh.w;
  uint2 pk;
  pk.x = (unsigned)f2bf(o0) | ((unsigned)f2bf(o1) << 16);
  pk.y = (unsigned)f2bf(o2) | ((unsigned)f2bf(o3) << 16);
  *(uint2*)(out + (size_t)row * D_ + tid * 4) = pk;
}

__global__ __launch_bounds__(256) void ln_mod_idx(const float* __restrict__ in,
                                                  const float* __restrict__ modv,
                                                  const int* __restrict__ cnt,
                                                  const int* __restrict__ cidx,
                                                  u16* __restrict__ out) {
  const int p = blockIdx.x;
  if (p >= *cnt) return;
  const int row = cidx[p];
  const int b = row >> 11;
  const int tid = threadIdx.x;
  const float4 v = *(const float4*)(in + (size_t)row * D_ + tid * 4);
  float s = v.x + v.y + v.z + v.w;
  float q = v.x * v.x + v.y * v.y + v.z * v.z + v.w * v.w;
#pragma unroll
  for (int off = 32; off > 0; off >>= 1) {
    s += __shfl_down(s, off);
    q += __shfl_down(q, off);
  }
  __shared__ float red[8];
  const int wave = tid >> 6, lane = tid & 63;
  if (lane == 0) { red[wave] = s; red[4 + wave] = q; }
  __syncthreads();
  float ts = red[0] + red[1] + red[2] + red[3];
  float tq = red[4] + red[5] + red[6] + red[7];
  const float mu = ts * (1.0f / D_);
  const float var = tq * (1.0f / D_) - mu * mu;
  const float rstd = rsqrtf(var + 1e-6f);
  const float4 sh = *(const float4*)(modv + (size_t)b * THREE_D + tid * 4);
  const float4 sc = *(const float4*)(modv + (size_t)b * THREE_D + D_ + tid * 4);
  float o0 = (v.x - mu) * rstd * (1.0f + sc.x) + sh.x;
  float o1 = (v.y - mu) * rstd * (1.0f + sc.y) + sh.y;
  float o2 = (v.z - mu) * rstd * (1.0f + sc.z) + sh.z;
  float o3 = (v.w - mu) * rstd * (1.0f + sc.w) + sh.w;
  uint2 pk;
  pk.x = (unsigned)f2bf(o0) | ((unsigned)f2bf(o1) << 16);
  pk.y = (unsigned)f2bf(o2) | ((unsigned)f2bf(o3) << 16);
  *(uint2*)(out + (size_t)p * D_ + tid * 4) = pk;
}

// ---------- bf16 MFMA GEMM, 256x256, 8 waves (r16 schedule) ----------------
// Block mapping:
//  EPI 1/3 (full M): XCD-swizzled (T1) — all blocks work, locality win.
//  EPI 0/2 (compacted, early-exit on *mpad): by = flat % NBY (FAST position)
//    so working blocks interleave uniformly across physical flat ids ->
//    all XCDs/CUs fed. (r18 bug: by in high bits culled flat&7>=4 -> XCDs
//    4-7 idle, occupancy 9.4%, zero speedup.)
constexpr int BM = 256, BN = 256, BK = 64;

template <int EPI, int NN, int KK>
__global__ __launch_bounds__(512, 2)
void gemm_bt(const u16* __restrict__ A, const u16* __restrict__ Bt,
             const float* __restrict__ b0, const float* __restrict__ b1,
             const float* __restrict__ xres, const int* __restrict__ cidx,
             const int* __restrict__ mpad,
             const float* __restrict__ gate,
             float* __restrict__ outf, u16* __restrict__ outh) {
  __shared__ u16 As[2][BM * BK];
  __shared__ u16 Bs[2][BN * BK];
  const int tid = threadIdx.x;
  const int wave = tid >> 6, lane = tid & 63;
  const int wr = wave >> 2, wc = wave & 3;
  const int l15 = lane & 15, l4 = lane >> 4;

  constexpr int LGX = (NN == 2048) ? 3 : 2;
  const int nwg = gridDim.x;
  const int flat = blockIdx.x;
  int bx, by;
  if constexpr (EPI == 0 || EPI == 2) {
    constexpr int NBY = M_ / BM;          // 64
    by = flat % NBY;                      // fast position: working blocks spread
    bx = flat / NBY;
  } else {
    const int swz = (flat & 7) * (nwg >> 3) + (flat >> 3);
    bx = swz & ((1 << LGX) - 1);
    by = swz >> LGX;
  }
  const int m0 = by * BM, n0 = bx * BN;

  if constexpr (EPI == 0 || EPI == 2) {
    if (m0 >= *mpad) return;              // compacted: data-dependent M
  }

  const int sg = (lane & 7) ^ (lane >> 3);
  const int srow = wave * 8 + (lane >> 3);
  const u16* ga = A  + (size_t)(m0 + srow) * KK + sg * 8;
  const u16* gb = Bt + (size_t)(n0 + srow) * KK + sg * 8;
  const int ldq = wave * 8 * BK;

  const int swz0 = ((l4 ^ (l15 & 7)) << 3);
  const int swz1 = (((4 + l4) ^ (l15 & 7)) << 3);
  const int arow = (wr * 128 + l15) * BK;
  const int brow = (wc * 64 + l15) * BK;

  f32x4 acc[8][4];
#pragma unroll
  for (int i = 0; i < 8; ++i)
#pragma unroll
    for (int j = 0; j < 4; ++j) acc[i][j] = (f32x4){0.f, 0.f, 0.f, 0.f};

  constexpr int NT = KK / BK;

#define STG_A(q, dst, gp) gload16((gp) + (size_t)((q) * 64) * KK, (dst) + ((q) * 64) * BK + ldq)
#define STG_B(q, dst, gp) gload16((gp) + (size_t)((q) * 64) * KK, (dst) + ((q) * 64) * BK + ldq)

  // prologue: stage tile 0 (L0 then M0), confirm L0, leave M0 flying
  STG_B(0, Bs[0], gb); STG_B(1, Bs[0], gb); STG_B(2, Bs[0], gb); STG_B(3, Bs[0], gb);
  STG_A(0, As[0], ga); STG_A(2, As[0], ga);
  STG_A(1, As[0], ga); STG_A(3, As[0], ga);
  asm volatile("s_waitcnt vmcnt(2)" ::: "memory");
  BAR();

  const u16* gan = ga + BK;
  const u16* gbn = gb + BK;

  bf16x8 af0[4], af1[4], bf0[4], bf1[4];
  for (int t = 0; t < NT; ++t) {
    const u16* as = As[t & 1];
    const u16* bs = Bs[t & 1];
    u16* An = As[(t + 1) & 1];
    u16* Bn = Bs[(t + 1) & 1];
    const bool pre = (t + 1 < NT);

    // ---- ph0 ----
#pragma unroll
    for (int i = 0; i < 4; ++i) af0[i] = ds_read128(as + arow + i * 16 * BK + swz0);
#pragma unroll
    for (int j = 0; j < 4; ++j) bf0[j] = ds_read128(bs + brow + j * 16 * BK + swz0);
    if (pre) { STG_B(0, Bn, gbn); STG_B(1, Bn, gbn); STG_B(2, Bn, gbn); STG_B(3, Bn, gbn); }
    LGKM0();
    __builtin_amdgcn_s_setprio(1);
#pragma unroll
    for (int i = 0; i < 4; ++i)
#pragma unroll
      for (int j = 0; j < 4; ++j)
        acc[i][j] = __builtin_amdgcn_mfma_f32_16x16x32_bf16(af0[i], bf0[j], acc[i][j], 0, 0, 0);
    __builtin_amdgcn_s_setprio(0);

    // ---- ph1 ----
#pragma unroll
    for (int i = 0; i < 4; ++i) af1[i] = ds_read128(as + arow + i * 16 * BK + swz1);
#pragma unroll
    for (int j = 0; j < 4; ++j) bf1[j] = ds_read128(bs + brow + j * 16 * BK + swz1);
    if (pre) {
      STG_A(0, An, gan); STG_A(2, An, gan);
      asm volatile("s_waitcnt vmcnt(6)" ::: "memory");   // M_t lands
    } else {
      asm volatile("s_waitcnt vmcnt(0)" ::: "memory");
    }
    BAR();
    LGKM0();
    __builtin_amdgcn_s_setprio(1);
#pragma unroll
    for (int i = 0; i < 4; ++i)
#pragma unroll
      for (int j = 0; j < 4; ++j)
        acc[i][j] = __builtin_amdgcn_mfma_f32_16x16x32_bf16(af1[i], bf1[j], acc[i][j], 0, 0, 0);
    __builtin_amdgcn_s_setprio(0);

    // ---- ph2 ----
#pragma unroll
    for (int i = 0; i < 4; ++i) af0[i] = ds_read128(as + arow + (64 + i * 16) * BK + swz0);
    if (pre) { STG_A(1, An, gan); STG_A(3, An, gan); }
    LGKM0();
    __builtin_amdgcn_s_setprio(1);
#pragma unroll
    for (int i = 0; i < 4; ++i)
#pragma unroll
      for (int j = 0; j < 4; ++j)
        acc[4 + i][j] = __builtin_amdgcn_mfma_f32_16x16x32_bf16(af0[i], bf0[j], acc[4 + i][j], 0, 0, 0);
    __builtin_amdgcn_s_setprio(0);

    // ---- ph3 ----
#pragma unroll
    for (int i = 0; i < 4; ++i) af1[i] = ds_read128(as + arow + (64 + i * 16) * BK + swz1);
    if (pre) asm volatile("s_waitcnt vmcnt(2)" ::: "memory");  // L_{t+1} lands
    BAR();
    LGKM0();
    __builtin_amdgcn_s_setprio(1);
#pragma unroll
    for (int i = 0; i < 4; ++i)
#pragma unroll
      for (int j = 0; j < 4; ++j)
        acc[4 + i][j] = __builtin_amdgcn_mfma_f32_16x16x32_bf16(af1[i], bf1[j], acc[4 + i][j], 0, 0, 0);
    __builtin_amdgcn_s_setprio(0);

    gan += BK; gbn += BK;
  }
#undef STG_A
#undef STG_B

#pragma unroll
  for (int i = 0; i < 8; ++i) {
#pragma unroll
    for (int r = 0; r < 4; ++r) {
      const int m = m0 + wr * 128 + i * 16 + l4 * 4 + r;   // compacted p for EPI 0/2
      int row = m;
      if constexpr (EPI == 2) {
        row = cidx[m];
        if (row < 0) continue;
      }
#pragma unroll
      for (int j = 0; j < 4; ++j) {
        const int n = n0 + wc * 64 + j * 16 + l15;
        float v = acc[i][j][r];
        if constexpr (EPI == 0 || EPI == 1) {
          v += (n < (NN >> 1)) ? b0[n] : b1[n - (NN >> 1)];
          outh[(size_t)m * NN + n] = f2bf(gelu_fast(v));
        } else if constexpr (EPI == 2) {
          v += b0[n] + b1[n];
          outf[(size_t)row * NN + n] = xres[(size_t)row * NN + n] +
                                       gate[(size_t)(row >> 11) * THREE_D + n] * v;
        } else {
          v += b0[n];
          outf[(size_t)m * NN + n] = outf[(size_t)m * NN + n] +
                                     gate[(size_t)(m >> 11) * THREE_D + n] * v;
        }
      }
    }
  }
}

}  // namespace

extern "C" void kernel_launch(void* const* d_in, const int* in_sizes, int n_in,
                              void* d_out, int out_size, void* d_ws, size_t ws_size,
                              hipStream_t stream) {
  const float* x       = (const float*)d_in[0];
  const float* t       = (const float*)d_in[1];
  const int*   mask    = (const int*)d_in[2];
  const float* ada_w   = (const float*)d_in[3];
  const float* ada_b   = (const float*)d_in[4];
  const float* ssm_w1  = (const float*)d_in[5];
  const float* ssm_b1  = (const float*)d_in[6];
  const float* ssm_w2  = (const float*)d_in[7];
  const float* ssm_b2  = (const float*)d_in[8];
  const float* bwd_w1  = (const float*)d_in[9];
  const float* bwd_b1  = (const float*)d_in[10];
  const float* bwd_w2  = (const float*)d_in[11];
  const float* bwd_b2  = (const float*)d_in[12];
  const float* ffada_w = (const float*)d_in[13];
  const float* ffada_b = (const float*)d_in[14];
  const float* ff_w1   = (const float*)d_in[15];
  const float* ff_b1   = (const float*)d_in[16];
  const float* ff_w2   = (const float*)d_in[17];
  const float* ff_b2   = (const float*)d_in[18];
  float* out = (float*)d_out;

  char* ws = (char*)d_ws;
  u16* normb = (u16*)ws;                                        // 16384*1024 bf16 (32 MB)
  u16* Hb    = (u16*)(ws + (size_t)M_ * D_ * 2);                // 16384*2048 bf16 (64 MB)
  u16* w1t   = (u16*)(ws + (size_t)M_ * D_ * 2 + (size_t)M_ * 2 * D_ * 2);
  u16* w2t   = w1t + (size_t)2 * D_ * D_;
  u16* fw1t  = w2t + (size_t)2 * D_ * D_;
  u16* fw2t  = fw1t + (size_t)2 * D_ * D_;
  float* emb   = (float*)(fw2t + (size_t)2 * D_ * D_);          // [8][3072]
  float* ffada = emb + B_ * THREE_D;                            // [8][3072]
  int* cnt   = (int*)(ffada + B_ * THREE_D);
  int* mpad  = cnt + 1;
  int* cidx  = mpad + 7;                                        // 16384 ints
  float* part0 = (float*)Hb;                                    // [4][8][3072]
  float* part1 = part0 + 4 * B_ * THREE_D;

  dim3 tb(32, 8);
  packT<<<dim3(64, 32), tb, 0, stream>>>(ssm_w1, bwd_w1, w1t, D_, 2 * D_, 1);
  packT<<<dim3(32, 64), tb, 0, stream>>>(ssm_w2, bwd_w2, w2t, 2 * D_, D_, 2);
  packT<<<dim3(64, 32), tb, 0, stream>>>(ff_w1, nullptr, fw1t, D_, 2 * D_, 0);
  packT<<<dim3(32, 64), tb, 0, stream>>>(ff_w2, nullptr, fw2t, 2 * D_, D_, 0);

  ada_part<<<dim3(12, 4), 256, 0, stream>>>(t, ada_w, part0);
  ada_part<<<dim3(12, 4), 256, 0, stream>>>(t, ffada_w, part1);
  ada_reduce<<<dim3(12, 8), 256, 0, stream>>>(part0, ada_b, emb);
  ada_reduce<<<dim3(12, 8), 256, 0, stream>>>(part1, ffada_b, ffada);

  // mask compaction for the SSM stage
  hipMemsetAsync(cnt, 0, sizeof(int), stream);
  compact_mask<<<64, 256, 0, stream>>>(mask, cnt, cidx);
  pad_tail<<<256, 256, 0, stream>>>(cnt, cidx, normb, mpad);
  copy_unmasked<<<M_, 256, 0, stream>>>(x, mask, out);          // x_mid = x for mask==0
  ln_mod_idx<<<M_, 256, 0, stream>>>(x, emb, cnt, cidx, normb); // compacted LN

  // H = gelu(norm @ W1cat + b1cat)   [M_pad x 2048], compacted rows
  gemm_bt<0, 2048, 1024><<<512, 512, 0, stream>>>(normb, w1t,
                                                  ssm_b1, bwd_b1, nullptr, nullptr, mpad, nullptr,
                                                  nullptr, Hb);
  // x_mid[row] = x[row] + gate_msa*(H @ W2cat + b2sum), scattered via cidx
  gemm_bt<2, 1024, 2048><<<256, 512, 0, stream>>>(Hb, w2t,
                                                  ssm_b2, bwd_b2, x, cidx, mpad, emb + 2 * D_,
                                                  out, nullptr);
  // ff stage: full M
  ln_mod<<<M_, 256, 0, stream>>>(out, ffada, normb);
  gemm_bt<1, 2048, 1024><<<512, 512, 0, stream>>>(normb, fw1t,
                                                  ff_b1, ff_b1 + D_, nullptr, nullptr, nullptr, nullptr,
                                                  nullptr, Hb);
  gemm_bt<3, 1024, 2048><<<256, 512, 0, stream>>>(Hb, fw2t,
                                                  ff_b2, nullptr, nullptr, nullptr, nullptr, ffada + 2 * D_,
                                                  out, nullptr);
}

// Round 20
// 382.240 us; speedup vs baseline: 1.1937x; 1.0330x over previous
//
#include <hip/hip_runtime.h>
#include <hip/hip_bf16.h>

namespace {

constexpr int D_      = 1024;
constexpr int THREE_D = 3072;
constexpr int B_      = 8;
constexpr int M_      = 16384;   // B*L tokens

typedef unsigned short u16;
typedef __attribute__((ext_vector_type(8))) short bf16x8;
typedef __attribute__((ext_vector_type(4))) float f32x4;

__device__ __forceinline__ u16 f2bf(float f) {
  unsigned u = __float_as_uint(f);
  u += 0x7fffu + ((u >> 16) & 1u);   // round-to-nearest-even
  return (u16)(u >> 16);
}
__device__ __forceinline__ float bf2f(u16 h) {
  return __uint_as_float(((unsigned)h) << 16);
}

__device__ __forceinline__ float gelu_fast(float x) {
  float u = 0.7978845608028654f * (x + 0.044715f * x * x * x);
  float e = __expf(2.0f * u);
  float th = 1.0f - 2.0f * __builtin_amdgcn_rcpf(e + 1.0f);
  return 0.5f * x * (1.0f + th);
}

typedef __attribute__((address_space(3))) unsigned int   lds_uint;
typedef const __attribute__((address_space(1))) unsigned int gl_uint;
__device__ __forceinline__ void gload16(const void* g, void* l) {
  __builtin_amdgcn_global_load_lds((gl_uint*)g, (lds_uint*)l, 16, 0, 0);
}

// inline-asm ds_read_b128 (avoids compiler's implicit vmcnt(0) drain before
// plain LDS reads while global_load_lds is outstanding — r15/r16 confirmed).
typedef __attribute__((address_space(3))) const u16 lds_cu16;
__device__ __forceinline__ bf16x8 ds_read128(const u16* p) {
  bf16x8 r;
  asm volatile("ds_read_b128 %0, %1" : "=v"(r) : "v"((lds_cu16*)p));
  return r;
}

#define BAR() asm volatile("s_barrier" ::: "memory")
#define LGKM0() do { asm volatile("s_waitcnt lgkmcnt(0)" ::: "memory"); \
                     __builtin_amdgcn_sched_barrier(0); } while (0)

// ---------- weight transpose + f32->bf16 pack ----------
__global__ void packT(const float* __restrict__ s0, const float* __restrict__ s1,
                      u16* __restrict__ dst, int K, int N, int mode) {
  __shared__ float tile[32][33];
  int n0 = blockIdx.x * 32, k0 = blockIdx.y * 32;
  int tx = threadIdx.x, ty = threadIdx.y;
  for (int i = ty; i < 32; i += 8) {
    int k = k0 + i, n = n0 + tx;
    float v;
    if (mode == 1)      { int h = N >> 1; v = (n < h) ? s0[(size_t)k * h + n] : s1[(size_t)k * h + (n - h)]; }
    else if (mode == 2) { int h = K >> 1; v = (k < h) ? s0[(size_t)k * N + n] : s1[(size_t)(k - h) * N + n]; }
    else                v = s0[(size_t)k * N + n];
    tile[i][tx] = v;
  }
  __syncthreads();
  for (int i = ty; i < 32; i += 8) {
    int n = n0 + i, k = k0 + tx;
    dst[(size_t)n * K + k] = f2bf(tile[tx][i]);
  }
}

// ---------- ada embedding, K-split ----------
__global__ __launch_bounds__(256) void ada_part(const float* __restrict__ t,
                                                const float* __restrict__ W,
                                                float* __restrict__ part) {
  __shared__ float s[B_ * 256];
  const int jb = blockIdx.x, kc = blockIdx.y;
  const int tid = threadIdx.x;
  const int k0 = kc * 256;
  for (int idx = tid; idx < B_ * 256; idx += 256) {
    float v = t[((idx >> 8) << 10) + k0 + (idx & 255)];
    s[idx] = v / (1.0f + expf(-v));
  }
  __syncthreads();
  const int j = jb * 256 + tid;
  float acc[B_];
#pragma unroll
  for (int b = 0; b < B_; ++b) acc[b] = 0.f;
  for (int k = 0; k < 256; ++k) {
    const float w = W[(size_t)(k0 + k) * THREE_D + j];
#pragma unroll
    for (int b = 0; b < B_; ++b) acc[b] = fmaf(s[(b << 8) + k], w, acc[b]);
  }
#pragma unroll
  for (int b = 0; b < B_; ++b)
    part[((size_t)kc * B_ + b) * THREE_D + j] = acc[b];
}

__global__ __launch_bounds__(256) void ada_reduce(const float* __restrict__ part,
                                                  const float* __restrict__ bias,
                                                  float* __restrict__ out) {
  const int j = blockIdx.x * 256 + threadIdx.x;
  const int b = blockIdx.y;
  float v = bias[j];
#pragma unroll
  for (int kc = 0; kc < 4; ++kc) v += part[((size_t)kc * B_ + b) * THREE_D + j];
  out[(size_t)b * THREE_D + j] = v;
}

// ---------- mask compaction ----------
__global__ __launch_bounds__(256) void compact_mask(const int* __restrict__ mask,
                                                    int* __restrict__ cnt,
                                                    int* __restrict__ cidx) {
  const int m = blockIdx.x * 256 + threadIdx.x;
  if (mask[m] != 0) {
    int p = atomicAdd(cnt, 1);
    cidx[p] = m;
  }
}

__global__ __launch_bounds__(256) void pad_tail(const int* __restrict__ cnt,
                                                int* __restrict__ cidx,
                                                u16* __restrict__ normc,
                                                int* __restrict__ mpad) {
  const int c = *cnt;
  const int pad = (c + 255) & ~255;
  if (blockIdx.x == 0 && threadIdx.x == 0) *mpad = pad;
  const int p = c + blockIdx.x;
  if (p < pad) {
    if (threadIdx.x == 0) cidx[p] = -1;
    ((uint2*)(normc + (size_t)p * D_))[threadIdx.x] = (uint2){0u, 0u};
  }
}

__global__ __launch_bounds__(256) void copy_unmasked(const float* __restrict__ x,
                                                     const int* __restrict__ mask,
                                                     float* __restrict__ out) {
  const int row = blockIdx.x;
  if (mask[row] != 0) return;
  const int tid = threadIdx.x;
  *(float4*)(out + (size_t)row * D_ + tid * 4) =
      *(const float4*)(x + (size_t)row * D_ + tid * 4);
}

// ---------- K-split combine: out[row] = x[row] + gate*(p0+p1+b2sum) --------
__global__ __launch_bounds__(256) void combine2(const u16* __restrict__ p0,
                                                const u16* __restrict__ p1,
                                                const float* __restrict__ x,
                                                const int* __restrict__ mpad,
                                                const int* __restrict__ cidx,
                                                const float* __restrict__ b0,
                                                const float* __restrict__ b1,
                                                const float* __restrict__ gate,
                                                float* __restrict__ out) {
  const int p = blockIdx.x;
  if (p >= *mpad) return;
  const int row = cidx[p];
  if (row < 0) return;
  const int j = threadIdx.x * 4;
  const uint2 a = *(const uint2*)(p0 + (size_t)p * D_ + j);
  const uint2 b = *(const uint2*)(p1 + (size_t)p * D_ + j);
  const float4 xv = *(const float4*)(x + (size_t)row * D_ + j);
  const float* gp = gate + (size_t)(row >> 11) * THREE_D + j;
  float4 o;
  o.x = xv.x + gp[0] * (bf2f((u16)(a.x & 0xffff)) + bf2f((u16)(b.x & 0xffff)) + b0[j]     + b1[j]);
  o.y = xv.y + gp[1] * (bf2f((u16)(a.x >> 16))    + bf2f((u16)(b.x >> 16))    + b0[j + 1] + b1[j + 1]);
  o.z = xv.z + gp[2] * (bf2f((u16)(a.y & 0xffff)) + bf2f((u16)(b.y & 0xffff)) + b0[j + 2] + b1[j + 2]);
  o.w = xv.w + gp[3] * (bf2f((u16)(a.y >> 16))    + bf2f((u16)(b.y >> 16))    + b0[j + 3] + b1[j + 3]);
  *(float4*)(out + (size_t)row * D_ + j) = o;
}

// ---------- LayerNorm + adaLN modulate -> bf16 (full M) ----------
__global__ __launch_bounds__(256) void ln_mod(const float* __restrict__ in,
                                              const float* __restrict__ modv,
                                              u16* __restrict__ out) {
  const int row = blockIdx.x;
  const int b = row >> 11;  // L = 2048
  const int tid = threadIdx.x;
  const float4 v = *(const float4*)(in + (size_t)row * D_ + tid * 4);
  float s = v.x + v.y + v.z + v.w;
  float q = v.x * v.x + v.y * v.y + v.z * v.z + v.w * v.w;
#pragma unroll
  for (int off = 32; off > 0; off >>= 1) {
    s += __shfl_down(s, off);
    q += __shfl_down(q, off);
  }
  __shared__ float red[8];
  const int wave = tid >> 6, lane = tid & 63;
  if (lane == 0) { red[wave] = s; red[4 + wave] = q; }
  __syncthreads();
  float ts = red[0] + red[1] + red[2] + red[3];
  float tq = red[4] + red[5] + red[6] + red[7];
  const float mu = ts * (1.0f / D_);
  const float var = tq * (1.0f / D_) - mu * mu;
  const float rstd = rsqrtf(var + 1e-6f);
  const float4 sh = *(const float4*)(modv + (size_t)b * THREE_D + tid * 4);
  const float4 sc = *(const float4*)(modv + (size_t)b * THREE_D + D_ + tid * 4);
  float o0 = (v.x - mu) * rstd * (1.0f + sc.x) + sh.x;
  float o1 = (v.y - mu) * rstd * (1.0f + sc.y) + sh.y;
  float o2 = (v.z - mu) * rstd * (1.0f + sc.z) + sh.z;
  float o3 = (v.w - mu) * rstd * (1.0f + sc.w) + sh.w;
  uint2 pk;
  pk.x = (unsigned)f2bf(o0) | ((unsigned)f2bf(o1) << 16);
  pk.y = (unsigned)f2bf(o2) | ((unsigned)f2bf(o3) << 16);
  *(uint2*)(out + (size_t)row * D_ + tid * 4) = pk;
}

__global__ __launch_bounds__(256) void ln_mod_idx(const float* __restrict__ in,
                                                  const float* __restrict__ modv,
                                                  const int* __restrict__ cnt,
                                                  const int* __restrict__ cidx,
                                                  u16* __restrict__ out) {
  const int p = blockIdx.x;
  if (p >= *cnt) return;
  const int row = cidx[p];
  const int b = row >> 11;
  const int tid = threadIdx.x;
  const float4 v = *(const float4*)(in + (size_t)row * D_ + tid * 4);
  float s = v.x + v.y + v.z + v.w;
  float q = v.x * v.x + v.y * v.y + v.z * v.z + v.w * v.w;
#pragma unroll
  for (int off = 32; off > 0; off >>= 1) {
    s += __shfl_down(s, off);
    q += __shfl_down(q, off);
  }
  __shared__ float red[8];
  const int wave = tid >> 6, lane = tid & 63;
  if (lane == 0) { red[wave] = s; red[4 + wave] = q; }
  __syncthreads();
  float ts = red[0] + red[1] + red[2] + red[3];
  float tq = red[4] + red[5] + red[6] + red[7];
  const float mu = ts * (1.0f / D_);
  const float var = tq * (1.0f / D_) - mu * mu;
  const float rstd = rsqrtf(var + 1e-6f);
  const float4 sh = *(const float4*)(modv + (size_t)b * THREE_D + tid * 4);
  const float4 sc = *(const float4*)(modv + (size_t)b * THREE_D + D_ + tid * 4);
  float o0 = (v.x - mu) * rstd * (1.0f + sc.x) + sh.x;
  float o1 = (v.y - mu) * rstd * (1.0f + sc.y) + sh.y;
  float o2 = (v.z - mu) * rstd * (1.0f + sc.z) + sh.z;
  float o3 = (v.w - mu) * rstd * (1.0f + sc.w) + sh.w;
  uint2 pk;
  pk.x = (unsigned)f2bf(o0) | ((unsigned)f2bf(o1) << 16);
  pk.y = (unsigned)f2bf(o2) | ((unsigned)f2bf(o3) << 16);
  *(uint2*)(out + (size_t)p * D_ + tid * 4) = pk;
}

// ---------- bf16 MFMA GEMM, 256x256, 8 waves (r16 schedule) ----------------
// EPI 0: compacted; outh = bf16(gelu(v + bias_split))
// EPI 1: full;      same epilogue
// EPI 3: full;      outf += gate*(v + b0)
// EPI 4: compacted K-SPLIT (g2c latency fix): grid (ks,bx,by) by-fastest,
//        ks = K-chunk of 1024 (16 tiles); raw bf16 partial -> outh/outh2.
//        Rationale: unsplit g2c had 128 working blocks (0.5/CU, half the
//        machine idle) x 32 serial tiles; split = 256 blocks (1/CU) x 16.
constexpr int BM = 256, BN = 256, BK = 64;

template <int EPI, int NN, int KK>
__global__ __launch_bounds__(512, 2)
void gemm_bt(const u16* __restrict__ A, const u16* __restrict__ Bt,
             const float* __restrict__ b0, const float* __restrict__ b1,
             const int* __restrict__ mpad,
             const float* __restrict__ gate,
             float* __restrict__ outf, u16* __restrict__ outh,
             u16* __restrict__ outh2) {
  __shared__ u16 As[2][BM * BK];
  __shared__ u16 Bs[2][BN * BK];
  const int tid = threadIdx.x;
  const int wave = tid >> 6, lane = tid & 63;
  const int wr = wave >> 2, wc = wave & 3;
  const int l15 = lane & 15, l4 = lane >> 4;

  constexpr int LGX = (NN == 2048) ? 3 : 2;
  const int nwg = gridDim.x;
  const int flat = blockIdx.x;
  int bx, by, ks = 0;
  if constexpr (EPI == 4) {
    by = flat & 63;                 // fast: working blocks spread over XCDs
    bx = (flat >> 6) & 3;
    ks = flat >> 8;                 // K-chunk 0/1
  } else if constexpr (EPI == 0) {
    constexpr int NBY = M_ / BM;    // 64
    by = flat % NBY;
    bx = flat / NBY;
  } else {
    const int swz = (flat & 7) * (nwg >> 3) + (flat >> 3);
    bx = swz & ((1 << LGX) - 1);
    by = swz >> LGX;
  }
  const int m0 = by * BM, n0 = bx * BN;

  if constexpr (EPI == 0 || EPI == 4) {
    if (m0 >= *mpad) return;        // compacted: data-dependent M
  }

  const int sg = (lane & 7) ^ (lane >> 3);
  const int srow = wave * 8 + (lane >> 3);
  const u16* ga = A  + (size_t)(m0 + srow) * KK + ks * 1024 + sg * 8;
  const u16* gb = Bt + (size_t)(n0 + srow) * KK + ks * 1024 + sg * 8;
  const int ldq = wave * 8 * BK;

  const int swz0 = ((l4 ^ (l15 & 7)) << 3);
  const int swz1 = (((4 + l4) ^ (l15 & 7)) << 3);
  const int arow = (wr * 128 + l15) * BK;
  const int brow = (wc * 64 + l15) * BK;

  f32x4 acc[8][4];
#pragma unroll
  for (int i = 0; i < 8; ++i)
#pragma unroll
    for (int j = 0; j < 4; ++j) acc[i][j] = (f32x4){0.f, 0.f, 0.f, 0.f};

  constexpr int NT = (EPI == 4) ? 16 : KK / BK;

#define STG_A(q, dst, gp) gload16((gp) + (size_t)((q) * 64) * KK, (dst) + ((q) * 64) * BK + ldq)
#define STG_B(q, dst, gp) gload16((gp) + (size_t)((q) * 64) * KK, (dst) + ((q) * 64) * BK + ldq)

  // prologue: stage tile 0 (L0 then M0), confirm L0, leave M0 flying
  STG_B(0, Bs[0], gb); STG_B(1, Bs[0], gb); STG_B(2, Bs[0], gb); STG_B(3, Bs[0], gb);
  STG_A(0, As[0], ga); STG_A(2, As[0], ga);
  STG_A(1, As[0], ga); STG_A(3, As[0], ga);
  asm volatile("s_waitcnt vmcnt(2)" ::: "memory");
  BAR();

  const u16* gan = ga + BK;
  const u16* gbn = gb + BK;

  bf16x8 af0[4], af1[4], bf0[4], bf1[4];
  for (int t = 0; t < NT; ++t) {
    const u16* as = As[t & 1];
    const u16* bs = Bs[t & 1];
    u16* An = As[(t + 1) & 1];
    u16* Bn = Bs[(t + 1) & 1];
    const bool pre = (t + 1 < NT);

    // ---- ph0 ----
#pragma unroll
    for (int i = 0; i < 4; ++i) af0[i] = ds_read128(as + arow + i * 16 * BK + swz0);
#pragma unroll
    for (int j = 0; j < 4; ++j) bf0[j] = ds_read128(bs + brow + j * 16 * BK + swz0);
    if (pre) { STG_B(0, Bn, gbn); STG_B(1, Bn, gbn); STG_B(2, Bn, gbn); STG_B(3, Bn, gbn); }
    LGKM0();
    __builtin_amdgcn_s_setprio(1);
#pragma unroll
    for (int i = 0; i < 4; ++i)
#pragma unroll
      for (int j = 0; j < 4; ++j)
        acc[i][j] = __builtin_amdgcn_mfma_f32_16x16x32_bf16(af0[i], bf0[j], acc[i][j], 0, 0, 0);
    __builtin_amdgcn_s_setprio(0);

    // ---- ph1 ----
#pragma unroll
    for (int i = 0; i < 4; ++i) af1[i] = ds_read128(as + arow + i * 16 * BK + swz1);
#pragma unroll
    for (int j = 0; j < 4; ++j) bf1[j] = ds_read128(bs + brow + j * 16 * BK + swz1);
    if (pre) {
      STG_A(0, An, gan); STG_A(2, An, gan);
      asm volatile("s_waitcnt vmcnt(6)" ::: "memory");   // M_t lands
    } else {
      asm volatile("s_waitcnt vmcnt(0)" ::: "memory");
    }
    BAR();
    LGKM0();
    __builtin_amdgcn_s_setprio(1);
#pragma unroll
    for (int i = 0; i < 4; ++i)
#pragma unroll
      for (int j = 0; j < 4; ++j)
        acc[i][j] = __builtin_amdgcn_mfma_f32_16x16x32_bf16(af1[i], bf1[j], acc[i][j], 0, 0, 0);
    __builtin_amdgcn_s_setprio(0);

    // ---- ph2 ----
#pragma unroll
    for (int i = 0; i < 4; ++i) af0[i] = ds_read128(as + arow + (64 + i * 16) * BK + swz0);
    if (pre) { STG_A(1, An, gan); STG_A(3, An, gan); }
    LGKM0();
    __builtin_amdgcn_s_setprio(1);
#pragma unroll
    for (int i = 0; i < 4; ++i)
#pragma unroll
      for (int j = 0; j < 4; ++j)
        acc[4 + i][j] = __builtin_amdgcn_mfma_f32_16x16x32_bf16(af0[i], bf0[j], acc[4 + i][j], 0, 0, 0);
    __builtin_amdgcn_s_setprio(0);

    // ---- ph3 ----
#pragma unroll
    for (int i = 0; i < 4; ++i) af1[i] = ds_read128(as + arow + (64 + i * 16) * BK + swz1);
    if (pre) asm volatile("s_waitcnt vmcnt(2)" ::: "memory");  // L_{t+1} lands
    BAR();
    LGKM0();
    __builtin_amdgcn_s_setprio(1);
#pragma unroll
    for (int i = 0; i < 4; ++i)
#pragma unroll
      for (int j = 0; j < 4; ++j)
        acc[4 + i][j] = __builtin_amdgcn_mfma_f32_16x16x32_bf16(af1[i], bf1[j], acc[4 + i][j], 0, 0, 0);
    __builtin_amdgcn_s_setprio(0);

    gan += BK; gbn += BK;
  }
#undef STG_A
#undef STG_B

  u16* ph = nullptr;
  if constexpr (EPI == 4) ph = (ks == 0) ? outh : outh2;

#pragma unroll
  for (int i = 0; i < 8; ++i) {
#pragma unroll
    for (int r = 0; r < 4; ++r) {
      const int m = m0 + wr * 128 + i * 16 + l4 * 4 + r;
#pragma unroll
      for (int j = 0; j < 4; ++j) {
        const int n = n0 + wc * 64 + j * 16 + l15;
        float v = acc[i][j][r];
        if constexpr (EPI == 0 || EPI == 1) {
          v += (n < (NN >> 1)) ? b0[n] : b1[n - (NN >> 1)];
          outh[(size_t)m * NN + n] = f2bf(gelu_fast(v));
        } else if constexpr (EPI == 4) {
          ph[(size_t)m * NN + n] = f2bf(v);       // raw partial; bias in combine
        } else {
          v += b0[n];
          outf[(size_t)m * NN + n] = outf[(size_t)m * NN + n] +
                                     gate[(size_t)(m >> 11) * THREE_D + n] * v;
        }
      }
    }
  }
}

}  // namespace

extern "C" void kernel_launch(void* const* d_in, const int* in_sizes, int n_in,
                              void* d_out, int out_size, void* d_ws, size_t ws_size,
                              hipStream_t stream) {
  const float* x       = (const float*)d_in[0];
  const float* t       = (const float*)d_in[1];
  const int*   mask    = (const int*)d_in[2];
  const float* ada_w   = (const float*)d_in[3];
  const float* ada_b   = (const float*)d_in[4];
  const float* ssm_w1  = (const float*)d_in[5];
  const float* ssm_b1  = (const float*)d_in[6];
  const float* ssm_w2  = (const float*)d_in[7];
  const float* ssm_b2  = (const float*)d_in[8];
  const float* bwd_w1  = (const float*)d_in[9];
  const float* bwd_b1  = (const float*)d_in[10];
  const float* bwd_w2  = (const float*)d_in[11];
  const float* bwd_b2  = (const float*)d_in[12];
  const float* ffada_w = (const float*)d_in[13];
  const float* ffada_b = (const float*)d_in[14];
  const float* ff_w1   = (const float*)d_in[15];
  const float* ff_b1   = (const float*)d_in[16];
  const float* ff_w2   = (const float*)d_in[17];
  const float* ff_b2   = (const float*)d_in[18];
  float* out = (float*)d_out;

  char* ws = (char*)d_ws;
  u16* normb = (u16*)ws;                                        // 32 MB (also p0)
  u16* Hb    = (u16*)(ws + (size_t)M_ * D_ * 2);                // 64 MB
  u16* w1t   = (u16*)(ws + (size_t)M_ * D_ * 2 + (size_t)M_ * 2 * D_ * 2);
  u16* w2t   = w1t + (size_t)2 * D_ * D_;
  u16* fw1t  = w2t + (size_t)2 * D_ * D_;
  u16* fw2t  = fw1t + (size_t)2 * D_ * D_;
  float* emb   = (float*)(fw2t + (size_t)2 * D_ * D_);          // [8][3072]
  float* ffada = emb + B_ * THREE_D;                            // [8][3072]
  int* cnt   = (int*)(ffada + B_ * THREE_D);
  int* mpad  = cnt + 1;
  int* cidx  = mpad + 7;                                        // 16384 ints
  u16* p1    = (u16*)(cidx + M_);                               // 32 MB K-split partial
  u16* p0    = normb;                                           // reuse (free during g2 split)
  float* part0 = (float*)Hb;                                    // ada partials (pre-GEMM)
  float* part1 = part0 + 4 * B_ * THREE_D;

  dim3 tb(32, 8);
  packT<<<dim3(64, 32), tb, 0, stream>>>(ssm_w1, bwd_w1, w1t, D_, 2 * D_, 1);
  packT<<<dim3(32, 64), tb, 0, stream>>>(ssm_w2, bwd_w2, w2t, 2 * D_, D_, 2);
  packT<<<dim3(64, 32), tb, 0, stream>>>(ff_w1, nullptr, fw1t, D_, 2 * D_, 0);
  packT<<<dim3(32, 64), tb, 0, stream>>>(ff_w2, nullptr, fw2t, 2 * D_, D_, 0);

  ada_part<<<dim3(12, 4), 256, 0, stream>>>(t, ada_w, part0);
  ada_part<<<dim3(12, 4), 256, 0, stream>>>(t, ffada_w, part1);
  ada_reduce<<<dim3(12, 8), 256, 0, stream>>>(part0, ada_b, emb);
  ada_reduce<<<dim3(12, 8), 256, 0, stream>>>(part1, ffada_b, ffada);

  // mask compaction for the SSM stage
  hipMemsetAsync(cnt, 0, sizeof(int), stream);
  compact_mask<<<64, 256, 0, stream>>>(mask, cnt, cidx);
  pad_tail<<<256, 256, 0, stream>>>(cnt, cidx, normb, mpad);
  copy_unmasked<<<M_, 256, 0, stream>>>(x, mask, out);          // x_mid = x for mask==0
  ln_mod_idx<<<M_, 256, 0, stream>>>(x, emb, cnt, cidx, normb); // compacted LN

  // H = gelu(norm @ W1cat + b1cat)   [M_pad x 2048], compacted rows
  gemm_bt<0, 2048, 1024><<<512, 512, 0, stream>>>(normb, w1t,
                                                  ssm_b1, bwd_b1, mpad, nullptr,
                                                  nullptr, Hb, nullptr);
  // K-split partials of H @ W2cat (raw, bf16): p0 = k<1024, p1 = k>=1024
  gemm_bt<4, 1024, 2048><<<512, 512, 0, stream>>>(Hb, w2t,
                                                  nullptr, nullptr, mpad, nullptr,
                                                  nullptr, p0, p1);
  // x_mid[row] = x[row] + gate_msa*(p0+p1+b2sum), scattered via cidx
  combine2<<<M_, 256, 0, stream>>>(p0, p1, x, mpad, cidx, ssm_b2, bwd_b2,
                                   emb + 2 * D_, out);

  // ff stage: full M
  ln_mod<<<M_, 256, 0, stream>>>(out, ffada, normb);
  gemm_bt<1, 2048, 1024><<<512, 512, 0, stream>>>(normb, fw1t,
                                                  ff_b1, ff_b1 + D_, nullptr, nullptr,
                                                  nullptr, Hb, nullptr);
  gemm_bt<3, 1024, 2048><<<256, 512, 0, stream>>>(Hb, fw2t,
                                                  ff_b2, nullptr, nullptr, ffada + 2 * D_,
                                                  out, nullptr, nullptr);
}

// Round 21
// 336.169 us; speedup vs baseline: 1.3573x; 1.1370x over previous
//
#include <hip/hip_runtime.h>
#include <hip/hip_bf16.h>

namespace {

constexpr int D_      = 1024;
constexpr int THREE_D = 3072;
constexpr int B_      = 8;
constexpr int M_      = 16384;   // B*L tokens

typedef unsigned short u16;
typedef __attribute__((ext_vector_type(8))) short bf16x8;
typedef __attribute__((ext_vector_type(4))) float f32x4;

__device__ __forceinline__ u16 f2bf(float f) {
  unsigned u = __float_as_uint(f);
  u += 0x7fffu + ((u >> 16) & 1u);   // round-to-nearest-even
  return (u16)(u >> 16);
}
__device__ __forceinline__ float bf2f(u16 h) {
  return __uint_as_float(((unsigned)h) << 16);
}

__device__ __forceinline__ float gelu_fast(float x) {
  float u = 0.7978845608028654f * (x + 0.044715f * x * x * x);
  float e = __expf(2.0f * u);
  float th = 1.0f - 2.0f * __builtin_amdgcn_rcpf(e + 1.0f);
  return 0.5f * x * (1.0f + th);
}

typedef __attribute__((address_space(3))) unsigned int   lds_uint;
typedef const __attribute__((address_space(1))) unsigned int gl_uint;
__device__ __forceinline__ void gload16(const void* g, void* l) {
  __builtin_amdgcn_global_load_lds((gl_uint*)g, (lds_uint*)l, 16, 0, 0);
}

// inline-asm ds_read_b128 (avoids compiler's implicit vmcnt(0) drain before
// plain LDS reads while global_load_lds is outstanding — r15/r16 confirmed).
typedef __attribute__((address_space(3))) const u16 lds_cu16;
__device__ __forceinline__ bf16x8 ds_read128(const u16* p) {
  bf16x8 r;
  asm volatile("ds_read_b128 %0, %1" : "=v"(r) : "v"((lds_cu16*)p));
  return r;
}

#define BAR() asm volatile("s_barrier" ::: "memory")
#define LGKM0() do { asm volatile("s_waitcnt lgkmcnt(0)" ::: "memory"); \
                     __builtin_amdgcn_sched_barrier(0); } while (0)

// ---------- weight transpose + f32->bf16 pack ----------
__global__ void packT(const float* __restrict__ s0, const float* __restrict__ s1,
                      u16* __restrict__ dst, int K, int N, int mode) {
  __shared__ float tile[32][33];
  int n0 = blockIdx.x * 32, k0 = blockIdx.y * 32;
  int tx = threadIdx.x, ty = threadIdx.y;
  for (int i = ty; i < 32; i += 8) {
    int k = k0 + i, n = n0 + tx;
    float v;
    if (mode == 1)      { int h = N >> 1; v = (n < h) ? s0[(size_t)k * h + n] : s1[(size_t)k * h + (n - h)]; }
    else if (mode == 2) { int h = K >> 1; v = (k < h) ? s0[(size_t)k * N + n] : s1[(size_t)(k - h) * N + n]; }
    else                v = s0[(size_t)k * N + n];
    tile[i][tx] = v;
  }
  __syncthreads();
  for (int i = ty; i < 32; i += 8) {
    int n = n0 + i, k = k0 + tx;
    dst[(size_t)n * K + k] = f2bf(tile[tx][i]);
  }
}

// ---------- ada embedding, K-split, both mats in one launch (grid.z) -------
__global__ __launch_bounds__(256) void ada_part(const float* __restrict__ t,
                                                const float* __restrict__ W0,
                                                const float* __restrict__ W1,
                                                float* __restrict__ part) {
  __shared__ float s[B_ * 256];
  const int jb = blockIdx.x, kc = blockIdx.y, z = blockIdx.z;
  const float* W = z ? W1 : W0;
  float* po = part + (size_t)z * 4 * B_ * THREE_D;
  const int tid = threadIdx.x;
  const int k0 = kc * 256;
  for (int idx = tid; idx < B_ * 256; idx += 256) {
    float v = t[((idx >> 8) << 10) + k0 + (idx & 255)];
    s[idx] = v / (1.0f + expf(-v));
  }
  __syncthreads();
  const int j = jb * 256 + tid;
  float acc[B_];
#pragma unroll
  for (int b = 0; b < B_; ++b) acc[b] = 0.f;
  for (int k = 0; k < 256; ++k) {
    const float w = W[(size_t)(k0 + k) * THREE_D + j];
#pragma unroll
    for (int b = 0; b < B_; ++b) acc[b] = fmaf(s[(b << 8) + k], w, acc[b]);
  }
#pragma unroll
  for (int b = 0; b < B_; ++b)
    po[((size_t)kc * B_ + b) * THREE_D + j] = acc[b];
}

__global__ __launch_bounds__(256) void ada_reduce(const float* __restrict__ part,
                                                  const float* __restrict__ bias0,
                                                  const float* __restrict__ bias1,
                                                  float* __restrict__ out0,
                                                  float* __restrict__ out1) {
  const int j = blockIdx.x * 256 + threadIdx.x;
  const int b = blockIdx.y, z = blockIdx.z;
  const float* pa = part + (size_t)z * 4 * B_ * THREE_D;
  float v = (z ? bias1 : bias0)[j];
#pragma unroll
  for (int kc = 0; kc < 4; ++kc) v += pa[((size_t)kc * B_ + b) * THREE_D + j];
  (z ? out1 : out0)[(size_t)b * THREE_D + j] = v;
}

// ---------- mask compaction (order nondeterministic; per-row arithmetic is
// position-independent -> bitwise-deterministic output) ----------
__global__ __launch_bounds__(256) void compact_mask(const int* __restrict__ mask,
                                                    int* __restrict__ cnt,
                                                    int* __restrict__ cidx,
                                                    int* __restrict__ pinv) {
  const int m = blockIdx.x * 256 + threadIdx.x;
  if (mask[m] != 0) {
    int p = atomicAdd(cnt, 1);
    cidx[p] = m;
    pinv[m] = p;
  }
}

__global__ void mpad_calc(const int* __restrict__ cnt, int* __restrict__ mpad) {
  *mpad = (*cnt + 255) & ~255;
}

// ---------- fused combine + unmasked copy (row space) ----------
// out[row] = mask ? x[row] + gate*(p0[pinv]+p1[pinv]+b2sum) : x[row]
__global__ __launch_bounds__(256) void combine_row(const u16* __restrict__ p0,
                                                   const u16* __restrict__ p1,
                                                   const float* __restrict__ x,
                                                   const int* __restrict__ mask,
                                                   const int* __restrict__ pinv,
                                                   const float* __restrict__ b0,
                                                   const float* __restrict__ b1,
                                                   const float* __restrict__ gate,
                                                   float* __restrict__ out) {
  const int row = blockIdx.x;
  const int j = threadIdx.x * 4;
  const float4 xv = *(const float4*)(x + (size_t)row * D_ + j);
  if (mask[row] == 0) {
    *(float4*)(out + (size_t)row * D_ + j) = xv;
    return;
  }
  const int p = pinv[row];
  const uint2 a = *(const uint2*)(p0 + (size_t)p * D_ + j);
  const uint2 b = *(const uint2*)(p1 + (size_t)p * D_ + j);
  const float* gp = gate + (size_t)(row >> 11) * THREE_D + j;
  float4 o;
  o.x = xv.x + gp[0] * (bf2f((u16)(a.x & 0xffff)) + bf2f((u16)(b.x & 0xffff)) + b0[j]     + b1[j]);
  o.y = xv.y + gp[1] * (bf2f((u16)(a.x >> 16))    + bf2f((u16)(b.x >> 16))    + b0[j + 1] + b1[j + 1]);
  o.z = xv.z + gp[2] * (bf2f((u16)(a.y & 0xffff)) + bf2f((u16)(b.y & 0xffff)) + b0[j + 2] + b1[j + 2]);
  o.w = xv.w + gp[3] * (bf2f((u16)(a.y >> 16))    + bf2f((u16)(b.y >> 16))    + b0[j + 3] + b1[j + 3]);
  *(float4*)(out + (size_t)row * D_ + j) = o;
}

// ---------- LayerNorm + adaLN modulate -> bf16 (full M) ----------
__global__ __launch_bounds__(256) void ln_mod(const float* __restrict__ in,
                                              const float* __restrict__ modv,
                                              u16* __restrict__ out) {
  const int row = blockIdx.x;
  const int b = row >> 11;  // L = 2048
  const int tid = threadIdx.x;
  const float4 v = *(const float4*)(in + (size_t)row * D_ + tid * 4);
  float s = v.x + v.y + v.z + v.w;
  float q = v.x * v.x + v.y * v.y + v.z * v.z + v.w * v.w;
#pragma unroll
  for (int off = 32; off > 0; off >>= 1) {
    s += __shfl_down(s, off);
    q += __shfl_down(q, off);
  }
  __shared__ float red[8];
  const int wave = tid >> 6, lane = tid & 63;
  if (lane == 0) { red[wave] = s; red[4 + wave] = q; }
  __syncthreads();
  float ts = red[0] + red[1] + red[2] + red[3];
  float tq = red[4] + red[5] + red[6] + red[7];
  const float mu = ts * (1.0f / D_);
  const float var = tq * (1.0f / D_) - mu * mu;
  const float rstd = rsqrtf(var + 1e-6f);
  const float4 sh = *(const float4*)(modv + (size_t)b * THREE_D + tid * 4);
  const float4 sc = *(const float4*)(modv + (size_t)b * THREE_D + D_ + tid * 4);
  float o0 = (v.x - mu) * rstd * (1.0f + sc.x) + sh.x;
  float o1 = (v.y - mu) * rstd * (1.0f + sc.y) + sh.y;
  float o2 = (v.z - mu) * rstd * (1.0f + sc.z) + sh.z;
  float o3 = (v.w - mu) * rstd * (1.0f + sc.w) + sh.w;
  uint2 pk;
  pk.x = (unsigned)f2bf(o0) | ((unsigned)f2bf(o1) << 16);
  pk.y = (unsigned)f2bf(o2) | ((unsigned)f2bf(o3) << 16);
  *(uint2*)(out + (size_t)row * D_ + tid * 4) = pk;
}

__global__ __launch_bounds__(256) void ln_mod_idx(const float* __restrict__ in,
                                                  const float* __restrict__ modv,
                                                  const int* __restrict__ cnt,
                                                  const int* __restrict__ cidx,
                                                  u16* __restrict__ out) {
  const int p = blockIdx.x;
  if (p >= *cnt) return;
  const int row = cidx[p];
  const int b = row >> 11;
  const int tid = threadIdx.x;
  const float4 v = *(const float4*)(in + (size_t)row * D_ + tid * 4);
  float s = v.x + v.y + v.z + v.w;
  float q = v.x * v.x + v.y * v.y + v.z * v.z + v.w * v.w;
#pragma unroll
  for (int off = 32; off > 0; off >>= 1) {
    s += __shfl_down(s, off);
    q += __shfl_down(q, off);
  }
  __shared__ float red[8];
  const int wave = tid >> 6, lane = tid & 63;
  if (lane == 0) { red[wave] = s; red[4 + wave] = q; }
  __syncthreads();
  float ts = red[0] + red[1] + red[2] + red[3];
  float tq = red[4] + red[5] + red[6] + red[7];
  const float mu = ts * (1.0f / D_);
  const float var = tq * (1.0f / D_) - mu * mu;
  const float rstd = rsqrtf(var + 1e-6f);
  const float4 sh = *(const float4*)(modv + (size_t)b * THREE_D + tid * 4);
  const float4 sc = *(const float4*)(modv + (size_t)b * THREE_D + D_ + tid * 4);
  float o0 = (v.x - mu) * rstd * (1.0f + sc.x) + sh.x;
  float o1 = (v.y - mu) * rstd * (1.0f + sc.y) + sh.y;
  float o2 = (v.z - mu) * rstd * (1.0f + sc.z) + sh.z;
  float o3 = (v.w - mu) * rstd * (1.0f + sc.w) + sh.w;
  uint2 pk;
  pk.x = (unsigned)f2bf(o0) | ((unsigned)f2bf(o1) << 16);
  pk.y = (unsigned)f2bf(o2) | ((unsigned)f2bf(o3) << 16);
  *(uint2*)(out + (size_t)p * D_ + tid * 4) = pk;
}

// ---------- bf16 MFMA GEMM, 256x256, 8 waves (r16 schedule; r20-identical) -
// EPI 0: compacted; outh = bf16(gelu(v + bias_split))
// EPI 1: full;      same epilogue
// EPI 3: full;      outf += gate*(v + b0)
// EPI 4: compacted K-SPLIT: grid (ks,bx,by) by-fastest; raw bf16 partials.
constexpr int BM = 256, BN = 256, BK = 64;

template <int EPI, int NN, int KK>
__global__ __launch_bounds__(512, 2)
void gemm_bt(const u16* __restrict__ A, const u16* __restrict__ Bt,
             const float* __restrict__ b0, const float* __restrict__ b1,
             const int* __restrict__ mpad,
             const float* __restrict__ gate,
             float* __restrict__ outf, u16* __restrict__ outh,
             u16* __restrict__ outh2) {
  __shared__ u16 As[2][BM * BK];
  __shared__ u16 Bs[2][BN * BK];
  const int tid = threadIdx.x;
  const int wave = tid >> 6, lane = tid & 63;
  const int wr = wave >> 2, wc = wave & 3;
  const int l15 = lane & 15, l4 = lane >> 4;

  constexpr int LGX = (NN == 2048) ? 3 : 2;
  const int nwg = gridDim.x;
  const int flat = blockIdx.x;
  int bx, by, ks = 0;
  if constexpr (EPI == 4) {
    by = flat & 63;                 // fast: working blocks spread over XCDs
    bx = (flat >> 6) & 3;
    ks = flat >> 8;                 // K-chunk 0/1
  } else if constexpr (EPI == 0) {
    constexpr int NBY = M_ / BM;    // 64
    by = flat % NBY;
    bx = flat / NBY;
  } else {
    const int swz = (flat & 7) * (nwg >> 3) + (flat >> 3);
    bx = swz & ((1 << LGX) - 1);
    by = swz >> LGX;
  }
  const int m0 = by * BM, n0 = bx * BN;

  if constexpr (EPI == 0 || EPI == 4) {
    if (m0 >= *mpad) return;        // compacted: data-dependent M
  }

  const int sg = (lane & 7) ^ (lane >> 3);
  const int srow = wave * 8 + (lane >> 3);
  const u16* ga = A  + (size_t)(m0 + srow) * KK + ks * 1024 + sg * 8;
  const u16* gb = Bt + (size_t)(n0 + srow) * KK + ks * 1024 + sg * 8;
  const int ldq = wave * 8 * BK;

  const int swz0 = ((l4 ^ (l15 & 7)) << 3);
  const int swz1 = (((4 + l4) ^ (l15 & 7)) << 3);
  const int arow = (wr * 128 + l15) * BK;
  const int brow = (wc * 64 + l15) * BK;

  f32x4 acc[8][4];
#pragma unroll
  for (int i = 0; i < 8; ++i)
#pragma unroll
    for (int j = 0; j < 4; ++j) acc[i][j] = (f32x4){0.f, 0.f, 0.f, 0.f};

  constexpr int NT = (EPI == 4) ? 16 : KK / BK;

#define STG_A(q, dst, gp) gload16((gp) + (size_t)((q) * 64) * KK, (dst) + ((q) * 64) * BK + ldq)
#define STG_B(q, dst, gp) gload16((gp) + (size_t)((q) * 64) * KK, (dst) + ((q) * 64) * BK + ldq)

  // prologue: stage tile 0 (L0 then M0), confirm L0, leave M0 flying
  STG_B(0, Bs[0], gb); STG_B(1, Bs[0], gb); STG_B(2, Bs[0], gb); STG_B(3, Bs[0], gb);
  STG_A(0, As[0], ga); STG_A(2, As[0], ga);
  STG_A(1, As[0], ga); STG_A(3, As[0], ga);
  asm volatile("s_waitcnt vmcnt(2)" ::: "memory");
  BAR();

  const u16* gan = ga + BK;
  const u16* gbn = gb + BK;

  bf16x8 af0[4], af1[4], bf0[4], bf1[4];
  for (int t = 0; t < NT; ++t) {
    const u16* as = As[t & 1];
    const u16* bs = Bs[t & 1];
    u16* An = As[(t + 1) & 1];
    u16* Bn = Bs[(t + 1) & 1];
    const bool pre = (t + 1 < NT);

    // ---- ph0 ----
#pragma unroll
    for (int i = 0; i < 4; ++i) af0[i] = ds_read128(as + arow + i * 16 * BK + swz0);
#pragma unroll
    for (int j = 0; j < 4; ++j) bf0[j] = ds_read128(bs + brow + j * 16 * BK + swz0);
    if (pre) { STG_B(0, Bn, gbn); STG_B(1, Bn, gbn); STG_B(2, Bn, gbn); STG_B(3, Bn, gbn); }
    LGKM0();
    __builtin_amdgcn_s_setprio(1);
#pragma unroll
    for (int i = 0; i < 4; ++i)
#pragma unroll
      for (int j = 0; j < 4; ++j)
        acc[i][j] = __builtin_amdgcn_mfma_f32_16x16x32_bf16(af0[i], bf0[j], acc[i][j], 0, 0, 0);
    __builtin_amdgcn_s_setprio(0);

    // ---- ph1 ----
#pragma unroll
    for (int i = 0; i < 4; ++i) af1[i] = ds_read128(as + arow + i * 16 * BK + swz1);
#pragma unroll
    for (int j = 0; j < 4; ++j) bf1[j] = ds_read128(bs + brow + j * 16 * BK + swz1);
    if (pre) {
      STG_A(0, An, gan); STG_A(2, An, gan);
      asm volatile("s_waitcnt vmcnt(6)" ::: "memory");   // M_t lands
    } else {
      asm volatile("s_waitcnt vmcnt(0)" ::: "memory");
    }
    BAR();
    LGKM0();
    __builtin_amdgcn_s_setprio(1);
#pragma unroll
    for (int i = 0; i < 4; ++i)
#pragma unroll
      for (int j = 0; j < 4; ++j)
        acc[i][j] = __builtin_amdgcn_mfma_f32_16x16x32_bf16(af1[i], bf1[j], acc[i][j], 0, 0, 0);
    __builtin_amdgcn_s_setprio(0);

    // ---- ph2 ----
#pragma unroll
    for (int i = 0; i < 4; ++i) af0[i] = ds_read128(as + arow + (64 + i * 16) * BK + swz0);
    if (pre) { STG_A(1, An, gan); STG_A(3, An, gan); }
    LGKM0();
    __builtin_amdgcn_s_setprio(1);
#pragma unroll
    for (int i = 0; i < 4; ++i)
#pragma unroll
      for (int j = 0; j < 4; ++j)
        acc[4 + i][j] = __builtin_amdgcn_mfma_f32_16x16x32_bf16(af0[i], bf0[j], acc[4 + i][j], 0, 0, 0);
    __builtin_amdgcn_s_setprio(0);

    // ---- ph3 ----
#pragma unroll
    for (int i = 0; i < 4; ++i) af1[i] = ds_read128(as + arow + (64 + i * 16) * BK + swz1);
    if (pre) asm volatile("s_waitcnt vmcnt(2)" ::: "memory");  // L_{t+1} lands
    BAR();
    LGKM0();
    __builtin_amdgcn_s_setprio(1);
#pragma unroll
    for (int i = 0; i < 4; ++i)
#pragma unroll
      for (int j = 0; j < 4; ++j)
        acc[4 + i][j] = __builtin_amdgcn_mfma_f32_16x16x32_bf16(af1[i], bf1[j], acc[4 + i][j], 0, 0, 0);
    __builtin_amdgcn_s_setprio(0);

    gan += BK; gbn += BK;
  }
#undef STG_A
#undef STG_B

  u16* ph = nullptr;
  if constexpr (EPI == 4) ph = (ks == 0) ? outh : outh2;

#pragma unroll
  for (int i = 0; i < 8; ++i) {
#pragma unroll
    for (int r = 0; r < 4; ++r) {
      const int m = m0 + wr * 128 + i * 16 + l4 * 4 + r;
#pragma unroll
      for (int j = 0; j < 4; ++j) {
        const int n = n0 + wc * 64 + j * 16 + l15;
        float v = acc[i][j][r];
        if constexpr (EPI == 0 || EPI == 1) {
          v += (n < (NN >> 1)) ? b0[n] : b1[n - (NN >> 1)];
          outh[(size_t)m * NN + n] = f2bf(gelu_fast(v));
        } else if constexpr (EPI == 4) {
          ph[(size_t)m * NN + n] = f2bf(v);       // raw partial; bias in combine
        } else {
          v += b0[n];
          outf[(size_t)m * NN + n] = outf[(size_t)m * NN + n] +
                                     gate[(size_t)(m >> 11) * THREE_D + n] * v;
        }
      }
    }
  }
}

}  // namespace

extern "C" void kernel_launch(void* const* d_in, const int* in_sizes, int n_in,
                              void* d_out, int out_size, void* d_ws, size_t ws_size,
                              hipStream_t stream) {
  const float* x       = (const float*)d_in[0];
  const float* t       = (const float*)d_in[1];
  const int*   mask    = (const int*)d_in[2];
  const float* ada_w   = (const float*)d_in[3];
  const float* ada_b   = (const float*)d_in[4];
  const float* ssm_w1  = (const float*)d_in[5];
  const float* ssm_b1  = (const float*)d_in[6];
  const float* ssm_w2  = (const float*)d_in[7];
  const float* ssm_b2  = (const float*)d_in[8];
  const float* bwd_w1  = (const float*)d_in[9];
  const float* bwd_b1  = (const float*)d_in[10];
  const float* bwd_w2  = (const float*)d_in[11];
  const float* bwd_b2  = (const float*)d_in[12];
  const float* ffada_w = (const float*)d_in[13];
  const float* ffada_b = (const float*)d_in[14];
  const float* ff_w1   = (const float*)d_in[15];
  const float* ff_b1   = (const float*)d_in[16];
  const float* ff_w2   = (const float*)d_in[17];
  const float* ff_b2   = (const float*)d_in[18];
  float* out = (float*)d_out;

  char* ws = (char*)d_ws;
  u16* normb = (u16*)ws;                                        // 32 MB (also p0)
  u16* Hb    = (u16*)(ws + (size_t)M_ * D_ * 2);                // 64 MB
  u16* w1t   = (u16*)(ws + (size_t)M_ * D_ * 2 + (size_t)M_ * 2 * D_ * 2);
  u16* w2t   = w1t + (size_t)2 * D_ * D_;
  u16* fw1t  = w2t + (size_t)2 * D_ * D_;
  u16* fw2t  = fw1t + (size_t)2 * D_ * D_;
  float* emb   = (float*)(fw2t + (size_t)2 * D_ * D_);          // [8][3072]
  float* ffada = emb + B_ * THREE_D;                            // [8][3072]
  int* cnt   = (int*)(ffada + B_ * THREE_D);
  int* mpad  = cnt + 1;
  int* cidx  = mpad + 7;                                        // 16384 ints
  int* pinv  = cidx + M_;                                       // 16384 ints
  u16* p1    = (u16*)(pinv + M_);                               // 32 MB K-split partial
  u16* p0    = normb;                                           // reuse (free during g4)
  float* apart = (float*)Hb;                                    // ada partials [2][4][8][3072]

  dim3 tb(32, 8);
  packT<<<dim3(64, 32), tb, 0, stream>>>(ssm_w1, bwd_w1, w1t, D_, 2 * D_, 1);
  packT<<<dim3(32, 64), tb, 0, stream>>>(ssm_w2, bwd_w2, w2t, 2 * D_, D_, 2);
  packT<<<dim3(64, 32), tb, 0, stream>>>(ff_w1, nullptr, fw1t, D_, 2 * D_, 0);
  packT<<<dim3(32, 64), tb, 0, stream>>>(ff_w2, nullptr, fw2t, 2 * D_, D_, 0);

  ada_part<<<dim3(12, 4, 2), 256, 0, stream>>>(t, ada_w, ffada_w, apart);
  ada_reduce<<<dim3(12, 8, 2), 256, 0, stream>>>(apart, ada_b, ffada_b, emb, ffada);

  // mask compaction for the SSM stage
  hipMemsetAsync(cnt, 0, sizeof(int), stream);
  compact_mask<<<64, 256, 0, stream>>>(mask, cnt, cidx, pinv);
  mpad_calc<<<1, 1, 0, stream>>>(cnt, mpad);
  ln_mod_idx<<<M_, 256, 0, stream>>>(x, emb, cnt, cidx, normb); // compacted LN

  // H = gelu(norm @ W1cat + b1cat)   [M_pad x 2048], compacted rows
  gemm_bt<0, 2048, 1024><<<512, 512, 0, stream>>>(normb, w1t,
                                                  ssm_b1, bwd_b1, mpad, nullptr,
                                                  nullptr, Hb, nullptr);
  // K-split partials of H @ W2cat (raw, bf16): p0 = k<1024, p1 = k>=1024
  gemm_bt<4, 1024, 2048><<<512, 512, 0, stream>>>(Hb, w2t,
                                                  nullptr, nullptr, mpad, nullptr,
                                                  nullptr, p0, p1);
  // x_mid = x + mask*gate_msa*(p0+p1+b2sum)  (all rows, fused unmasked copy)
  combine_row<<<M_, 256, 0, stream>>>(p0, p1, x, mask, pinv, ssm_b2, bwd_b2,
                                      emb + 2 * D_, out);

  // ff stage: full M
  ln_mod<<<M_, 256, 0, stream>>>(out, ffada, normb);
  gemm_bt<1, 2048, 1024><<<512, 512, 0, stream>>>(normb, fw1t,
                                                  ff_b1, ff_b1 + D_, nullptr, nullptr,
                                                  nullptr, Hb, nullptr);
  gemm_bt<3, 1024, 2048><<<256, 512, 0, stream>>>(Hb, fw2t,
                                                  ff_b2, nullptr, nullptr, ffada + 2 * D_,
                                                  out, nullptr, nullptr);
}